// Round 1
// baseline (728.618 us; speedup 1.0000x reference)
//
#include <hip/hip_runtime.h>

#define NN 50000
#define NE 1600000
#define EP (NE + NN)          // edges + self loops = 1,650,000
#define INC 64
#define TDIM 32
#define INDIM 96
#define D1 128
#define NEG 0.2f

__device__ __forceinline__ float lrelu(float v) { return v > 0.f ? v : NEG * v; }

// ---- GEMM0: h=[x | W_time[ts]];  xl0 = h@Wl0+bl0 ; xr0 = h@Wr0+br0  (cols in regs)
__global__ __launch_bounds__(256) void k_gemm0(
    const float* __restrict__ x, const int* __restrict__ ts,
    const float* __restrict__ Wt,
    const float* __restrict__ Wl, const float* __restrict__ bl,
    const float* __restrict__ Wr, const float* __restrict__ br,
    float* __restrict__ xl0, float* __restrict__ xr0)
{
    const int t = threadIdx.x;
    const int col = t & 127;
    const bool isR = (t >= 128);
    const float* __restrict__ W = isR ? Wr : Wl;
    float wreg[INDIM];
#pragma unroll
    for (int k = 0; k < INDIM; ++k) wreg[k] = W[k * D1 + col];
    const float bias = isR ? br[col] : bl[col];
    float* __restrict__ outp = isR ? xr0 : xl0;

    __shared__ float hs[8][INDIM];
    const int tiles = (NN + 7) / 8;
    for (int tile = blockIdx.x; tile < tiles; tile += gridDim.x) {
        const int base = tile * 8;
        __syncthreads();
#pragma unroll
        for (int j = 0; j < 3; ++j) {
            int flat = j * 256 + t;        // 0..767 covers 8*96
            int nd = flat / INDIM;
            int k = flat - nd * INDIM;
            int n = base + nd;
            float v = 0.f;
            if (n < NN)
                v = (k < INC) ? x[(size_t)n * INC + k]
                              : Wt[(size_t)ts[n] * TDIM + (k - INC)];
            hs[nd][k] = v;
        }
        __syncthreads();
#pragma unroll
        for (int nd = 0; nd < 8; ++nd) {
            int n = base + nd;
            if (n >= NN) break;
            const float4* hp = reinterpret_cast<const float4*>(&hs[nd][0]);
            float acc = bias;
#pragma unroll
            for (int k4 = 0; k4 < INDIM / 4; ++k4) {
                float4 hv = hp[k4];
                acc += wreg[4*k4+0]*hv.x + wreg[4*k4+1]*hv.y
                     + wreg[4*k4+2]*hv.z + wreg[4*k4+3]*hv.w;
            }
            outp[(size_t)n * D1 + col] = acc;
        }
    }
}

// ---- degree histogram over dst
__global__ __launch_bounds__(256) void k_deg(const int* __restrict__ ei, int* __restrict__ deg)
{
    int e = blockIdx.x * 256 + threadIdx.x;
    if (e >= EP) return;
    int d = (e < NE) ? ei[NE + e] : (e - NE);
    atomicAdd(&deg[d], 1);
}

// ---- single-block exclusive scan: deg -> row_start, cursor
__global__ __launch_bounds__(1024) void k_scan(
    const int* __restrict__ deg, int* __restrict__ rowst, int* __restrict__ cursor)
{
    __shared__ int sums[1024];
    const int t = threadIdx.x;
    const int chunk = (NN + 1023) / 1024;   // 49
    const int base = t * chunk;
    int s = 0;
    for (int i = 0; i < chunk; ++i) {
        int idx = base + i;
        if (idx < NN) s += deg[idx];
    }
    sums[t] = s;
    __syncthreads();
    for (int off = 1; off < 1024; off <<= 1) {
        int add = (t >= off) ? sums[t - off] : 0;
        __syncthreads();
        sums[t] += add;
        __syncthreads();
    }
    int run = sums[t] - s;   // exclusive prefix
    for (int i = 0; i < chunk; ++i) {
        int idx = base + i;
        if (idx < NN) {
            rowst[idx] = run;
            cursor[idx] = run;
            run += deg[idx];
        }
    }
    if (t == 0) rowst[NN] = EP;
}

// ---- scatter edge ids into CSR-by-dst
__global__ __launch_bounds__(256) void k_scatter(
    const int* __restrict__ ei, int* __restrict__ cursor, int* __restrict__ csr)
{
    int e = blockIdx.x * 256 + threadIdx.x;
    if (e >= EP) return;
    int d = (e < NE) ? ei[NE + e] : (e - NE);
    int pos = atomicAdd(&cursor[d], 1);
    csr[pos] = e;
}

// ---- layer-0 fused: per-dst wave; logits + softmax-normalized aggregation + bias + relu
__global__ __launch_bounds__(256) void k_agg0(
    const int* __restrict__ ei, const int* __restrict__ rowst,
    const int* __restrict__ csr,
    const float* __restrict__ xl0, const float* __restrict__ xr0,
    const float* __restrict__ att0, const float* __restrict__ bias0,
    float* __restrict__ h1)
{
    const int d = (blockIdx.x * 256 + threadIdx.x) >> 6;
    const int lane = threadIdx.x & 63;
    if (d >= NN) return;
    const int c = lane * 2;                 // this lane owns channels c, c+1 (head = lane/16)
    float2 xr = *reinterpret_cast<const float2*>(xr0 + (size_t)d * D1 + c);
    float2 at = *reinterpret_cast<const float2*>(att0 + c);
    const int rs = rowst[d], re = rowst[d + 1];
    float accx = 0.f, accy = 0.f, wsum = 0.f;
    int e = (rs < re) ? csr[rs] : 0;
    int s = (e < NE) ? ei[e] : (e - NE);
    for (int i = rs; i < re; ++i) {
        int e2 = 0, s2 = 0;
        if (i + 1 < re) {                    // prefetch next edge's indices
            e2 = csr[i + 1];
            s2 = (e2 < NE) ? ei[e2] : (e2 - NE);
        }
        float2 xs = *reinterpret_cast<const float2*>(xl0 + (size_t)s * D1 + c);
        float p = lrelu(xs.x + xr.x) * at.x + lrelu(xs.y + xr.y) * at.y;
        p += __shfl_xor(p, 1);
        p += __shfl_xor(p, 2);
        p += __shfl_xor(p, 4);
        p += __shfl_xor(p, 8);               // 16-lane (one head) reduction
        float wgt = __expf(p);               // no max-subtraction needed: |logit| <~ 6
        wsum += wgt;
        accx += wgt * xs.x;
        accy += wgt * xs.y;
        e = e2; s = s2;
    }
    float r = 1.f / (wsum + 1e-16f);
    h1[(size_t)d * D1 + c]     = fmaxf(accx * r + bias0[c], 0.f);
    h1[(size_t)d * D1 + c + 1] = fmaxf(accy * r + bias0[c + 1], 0.f);
}

// ---- GEMM1: xl1 = h1@Wl1+bl1 ; xr1 = h1@Wr1+br1   (thread per node)
__global__ __launch_bounds__(256) void k_gemm1(
    const float* __restrict__ h1,
    const float* __restrict__ Wl, const float* __restrict__ bl,
    const float* __restrict__ Wr, const float* __restrict__ br,
    float* __restrict__ xl1, float* __restrict__ xr1)
{
    __shared__ float wls[D1 * 2], wrs[D1 * 2];
    const int t = threadIdx.x;
    wls[t] = Wl[t]; wrs[t] = Wr[t];          // 256 threads load 256 floats each array
    __syncthreads();
    int n = blockIdx.x * 256 + t;
    if (n >= NN) return;
    float al0 = bl[0], al1 = bl[1], ar0 = br[0], ar1 = br[1];
    const float4* hp = reinterpret_cast<const float4*>(h1 + (size_t)n * D1);
    const float2* wl2 = reinterpret_cast<const float2*>(wls);
    const float2* wr2 = reinterpret_cast<const float2*>(wrs);
#pragma unroll
    for (int k4 = 0; k4 < D1 / 4; ++k4) {
        float4 hv = hp[k4];
        int k = k4 * 4;
        float2 a, b;
        a = wl2[k+0]; b = wr2[k+0]; al0 += hv.x*a.x; al1 += hv.x*a.y; ar0 += hv.x*b.x; ar1 += hv.x*b.y;
        a = wl2[k+1]; b = wr2[k+1]; al0 += hv.y*a.x; al1 += hv.y*a.y; ar0 += hv.y*b.x; ar1 += hv.y*b.y;
        a = wl2[k+2]; b = wr2[k+2]; al0 += hv.z*a.x; al1 += hv.z*a.y; ar0 += hv.z*b.x; ar1 += hv.z*b.y;
        a = wl2[k+3]; b = wr2[k+3]; al0 += hv.w*a.x; al1 += hv.w*a.y; ar0 += hv.w*b.x; ar1 += hv.w*b.y;
    }
    *reinterpret_cast<float2*>(xl1 + (size_t)n * 2) = make_float2(al0, al1);
    *reinterpret_cast<float2*>(xr1 + (size_t)n * 2) = make_float2(ar0, ar1);
}

// ---- layer-1 fused: thread per dst; single loop, normalize at end
__global__ __launch_bounds__(256) void k_layer1(
    const int* __restrict__ ei, const int* __restrict__ rowst,
    const int* __restrict__ csr,
    const float* __restrict__ xl1, const float* __restrict__ xr1,
    const float* __restrict__ att1, const float* __restrict__ bias1,
    float* __restrict__ out)
{
    int d = blockIdx.x * 256 + threadIdx.x;
    if (d >= NN) return;
    float2 xr = *reinterpret_cast<const float2*>(xr1 + (size_t)d * 2);
    float A0 = att1[0], A1 = att1[1];
    int rs = rowst[d], re = rowst[d + 1];
    float sum = 0.f, a0 = 0.f, a1 = 0.f;
    for (int i = rs; i < re; ++i) {
        int e = csr[i];
        int s = (e < NE) ? ei[e] : (e - NE);
        float2 xs = *reinterpret_cast<const float2*>(xl1 + (size_t)s * 2);
        float wgt = __expf(lrelu(xs.x + xr.x) * A0 + lrelu(xs.y + xr.y) * A1);
        sum += wgt;
        a0 += wgt * xs.x;
        a1 += wgt * xs.y;
    }
    float r = 1.f / (sum + 1e-16f);
    out[(size_t)d * 2]     = a0 * r + bias1[0];
    out[(size_t)d * 2 + 1] = a1 * r + bias1[1];
}

extern "C" void kernel_launch(void* const* d_in, const int* in_sizes, int n_in,
                              void* d_out, int out_size, void* d_ws, size_t ws_size,
                              hipStream_t stream)
{
    const float* x     = (const float*)d_in[0];
    const int*   ei    = (const int*)d_in[1];
    const int*   ts    = (const int*)d_in[2];
    const float* Wt    = (const float*)d_in[3];
    const float* Wl0   = (const float*)d_in[4];
    const float* bl0   = (const float*)d_in[5];
    const float* Wr0   = (const float*)d_in[6];
    const float* br0   = (const float*)d_in[7];
    const float* att0  = (const float*)d_in[8];
    const float* bias0 = (const float*)d_in[9];
    const float* Wl1   = (const float*)d_in[10];
    const float* bl1   = (const float*)d_in[11];
    const float* Wr1   = (const float*)d_in[12];
    const float* br1   = (const float*)d_in[13];
    const float* att1  = (const float*)d_in[14];
    const float* bias1 = (const float*)d_in[15];
    float* out = (float*)d_out;

    char* wsp = (char*)d_ws;
    size_t off = 0;
    auto alloc = [&](size_t bytes) -> void* {
        void* p = wsp + off;
        off += (bytes + 255) & ~(size_t)255;
        return p;
    };
    float* xl0   = (float*)alloc((size_t)NN * D1 * 4);
    float* xr0   = (float*)alloc((size_t)NN * D1 * 4);
    float* h1    = (float*)alloc((size_t)NN * D1 * 4);
    float* xl1   = (float*)alloc((size_t)NN * 2 * 4);
    float* xr1   = (float*)alloc((size_t)NN * 2 * 4);
    int* deg     = (int*)alloc((size_t)NN * 4);
    int* rowst   = (int*)alloc((size_t)(NN + 1) * 4);
    int* cursor  = (int*)alloc((size_t)NN * 4);
    int* csr     = (int*)alloc((size_t)EP * 4);

    hipMemsetAsync(deg, 0, (size_t)NN * 4, stream);

    k_gemm0<<<512, 256, 0, stream>>>(x, ts, Wt, Wl0, bl0, Wr0, br0, xl0, xr0);
    k_deg<<<(EP + 255) / 256, 256, 0, stream>>>(ei, deg);
    k_scan<<<1, 1024, 0, stream>>>(deg, rowst, cursor);
    k_scatter<<<(EP + 255) / 256, 256, 0, stream>>>(ei, cursor, csr);
    k_agg0<<<(NN + 3) / 4, 256, 0, stream>>>(ei, rowst, csr, xl0, xr0, att0, bias0, h1);
    k_gemm1<<<(NN + 255) / 256, 256, 0, stream>>>(h1, Wl1, bl1, Wr1, br1, xl1, xr1);
    k_layer1<<<(NN + 255) / 256, 256, 0, stream>>>(ei, rowst, csr, xl1, xr1, att1, bias1, out);
}

// Round 2
// 515.405 us; speedup vs baseline: 1.4137x; 1.4137x over previous
//
#include <hip/hip_runtime.h>

#define NN 50000
#define NE 1600000
#define EP (NE + NN)          // edges + self loops = 1,650,000
#define INC 64
#define TDIM 32
#define INDIM 96
#define D1 128
#define NEG 0.2f

__device__ __forceinline__ float lrelu(float v) { return v > 0.f ? v : NEG * v; }

// ---- GEMM0: h=[x | W_time[ts]];  xl0 = h@Wl0+bl0 ; xr0 = h@Wr0+br0  (cols in regs)
__global__ __launch_bounds__(256) void k_gemm0(
    const float* __restrict__ x, const int* __restrict__ ts,
    const float* __restrict__ Wt,
    const float* __restrict__ Wl, const float* __restrict__ bl,
    const float* __restrict__ Wr, const float* __restrict__ br,
    float* __restrict__ xl0, float* __restrict__ xr0)
{
    const int t = threadIdx.x;
    const int col = t & 127;
    const bool isR = (t >= 128);
    const float* __restrict__ W = isR ? Wr : Wl;
    float wreg[INDIM];
#pragma unroll
    for (int k = 0; k < INDIM; ++k) wreg[k] = W[k * D1 + col];
    const float bias = isR ? br[col] : bl[col];
    float* __restrict__ outp = isR ? xr0 : xl0;

    __shared__ float hs[8][INDIM];
    const int tiles = (NN + 7) / 8;
    for (int tile = blockIdx.x; tile < tiles; tile += gridDim.x) {
        const int base = tile * 8;
        __syncthreads();
#pragma unroll
        for (int j = 0; j < 3; ++j) {
            int flat = j * 256 + t;        // 0..767 covers 8*96
            int nd = flat / INDIM;
            int k = flat - nd * INDIM;
            int n = base + nd;
            float v = 0.f;
            if (n < NN)
                v = (k < INC) ? x[(size_t)n * INC + k]
                              : Wt[(size_t)ts[n] * TDIM + (k - INC)];
            hs[nd][k] = v;
        }
        __syncthreads();
#pragma unroll
        for (int nd = 0; nd < 8; ++nd) {
            int n = base + nd;
            if (n >= NN) break;
            const float4* hp = reinterpret_cast<const float4*>(&hs[nd][0]);
            float acc = bias;
#pragma unroll
            for (int k4 = 0; k4 < INDIM / 4; ++k4) {
                float4 hv = hp[k4];
                acc += wreg[4*k4+0]*hv.x + wreg[4*k4+1]*hv.y
                     + wreg[4*k4+2]*hv.z + wreg[4*k4+3]*hv.w;
            }
            outp[(size_t)n * D1 + col] = acc;
        }
    }
}

// ---- degree histogram over dst
__global__ __launch_bounds__(256) void k_deg(const int* __restrict__ ei, int* __restrict__ deg)
{
    int e = blockIdx.x * 256 + threadIdx.x;
    if (e >= EP) return;
    int d = (e < NE) ? ei[NE + e] : (e - NE);
    atomicAdd(&deg[d], 1);
}

// ---- single-block exclusive scan: deg -> row_start, cursor
__global__ __launch_bounds__(1024) void k_scan(
    const int* __restrict__ deg, int* __restrict__ rowst, int* __restrict__ cursor)
{
    __shared__ int sums[1024];
    const int t = threadIdx.x;
    const int chunk = (NN + 1023) / 1024;   // 49
    const int base = t * chunk;
    int s = 0;
    for (int i = 0; i < chunk; ++i) {
        int idx = base + i;
        if (idx < NN) s += deg[idx];
    }
    sums[t] = s;
    __syncthreads();
    for (int off = 1; off < 1024; off <<= 1) {
        int add = (t >= off) ? sums[t - off] : 0;
        __syncthreads();
        sums[t] += add;
        __syncthreads();
    }
    int run = sums[t] - s;   // exclusive prefix
    for (int i = 0; i < chunk; ++i) {
        int idx = base + i;
        if (idx < NN) {
            rowst[idx] = run;
            cursor[idx] = run;
            run += deg[idx];
        }
    }
    if (t == 0) rowst[NN] = EP;
}

// ---- scatter SRC node ids into CSR-by-dst (resolve edge->src here, once)
__global__ __launch_bounds__(256) void k_scatter(
    const int* __restrict__ ei, int* __restrict__ cursor, int* __restrict__ csr)
{
    int e = blockIdx.x * 256 + threadIdx.x;
    if (e >= EP) return;
    int d, s;
    if (e < NE) { d = ei[NE + e]; s = ei[e]; }
    else        { d = e - NE;     s = e - NE; }
    int pos = atomicAdd(&cursor[d], 1);
    csr[pos] = s;
}

// ---- layer-0 fused: per-dst wave; 8-deep pipelined gather + softmax-free norm
__global__ __launch_bounds__(256) void k_agg0(
    const int* __restrict__ rowst, const int* __restrict__ csr,
    const float* __restrict__ xl0, const float* __restrict__ xr0,
    const float* __restrict__ att0, const float* __restrict__ bias0,
    float* __restrict__ h1)
{
    const int d = (blockIdx.x * 256 + threadIdx.x) >> 6;
    const int lane = threadIdx.x & 63;
    if (d >= NN) return;
    const int c = lane * 2;                 // this lane owns channels c, c+1 (head = lane/16)
    float2 xr = *reinterpret_cast<const float2*>(xr0 + (size_t)d * D1 + c);
    float2 at = *reinterpret_cast<const float2*>(att0 + c);
    const int rs = rowst[d], re = rowst[d + 1];
    float accx = 0.f, accy = 0.f, wsum = 0.f;

    int i = rs;
    for (; i + 8 <= re; i += 8) {
        int s[8];
#pragma unroll
        for (int j = 0; j < 8; ++j) s[j] = csr[i + j];
        float2 xs[8];
#pragma unroll
        for (int j = 0; j < 8; ++j)
            xs[j] = *reinterpret_cast<const float2*>(xl0 + (size_t)s[j] * D1 + c);
#pragma unroll
        for (int j = 0; j < 8; ++j) {
            float p = lrelu(xs[j].x + xr.x) * at.x + lrelu(xs[j].y + xr.y) * at.y;
            p += __shfl_xor(p, 1);
            p += __shfl_xor(p, 2);
            p += __shfl_xor(p, 4);
            p += __shfl_xor(p, 8);          // 16-lane (one head) reduction
            float wgt = __expf(p);          // |logit| small: no max-subtraction needed
            wsum += wgt;
            accx += wgt * xs[j].x;
            accy += wgt * xs[j].y;
        }
    }
    for (; i < re; ++i) {
        int s = csr[i];
        float2 xs = *reinterpret_cast<const float2*>(xl0 + (size_t)s * D1 + c);
        float p = lrelu(xs.x + xr.x) * at.x + lrelu(xs.y + xr.y) * at.y;
        p += __shfl_xor(p, 1);
        p += __shfl_xor(p, 2);
        p += __shfl_xor(p, 4);
        p += __shfl_xor(p, 8);
        float wgt = __expf(p);
        wsum += wgt;
        accx += wgt * xs.x;
        accy += wgt * xs.y;
    }
    float r = 1.f / (wsum + 1e-16f);
    h1[(size_t)d * D1 + c]     = fmaxf(accx * r + bias0[c], 0.f);
    h1[(size_t)d * D1 + c + 1] = fmaxf(accy * r + bias0[c + 1], 0.f);
}

// ---- GEMM1: xl1 = h1@Wl1+bl1 ; xr1 = h1@Wr1+br1   (thread per node)
__global__ __launch_bounds__(256) void k_gemm1(
    const float* __restrict__ h1,
    const float* __restrict__ Wl, const float* __restrict__ bl,
    const float* __restrict__ Wr, const float* __restrict__ br,
    float* __restrict__ xl1, float* __restrict__ xr1)
{
    __shared__ float wls[D1 * 2], wrs[D1 * 2];
    const int t = threadIdx.x;
    wls[t] = Wl[t]; wrs[t] = Wr[t];          // 256 threads load 256 floats each array
    __syncthreads();
    int n = blockIdx.x * 256 + t;
    if (n >= NN) return;
    float al0 = bl[0], al1 = bl[1], ar0 = br[0], ar1 = br[1];
    const float4* hp = reinterpret_cast<const float4*>(h1 + (size_t)n * D1);
    const float2* wl2 = reinterpret_cast<const float2*>(wls);
    const float2* wr2 = reinterpret_cast<const float2*>(wrs);
#pragma unroll
    for (int k4 = 0; k4 < D1 / 4; ++k4) {
        float4 hv = hp[k4];
        int k = k4 * 4;
        float2 a, b;
        a = wl2[k+0]; b = wr2[k+0]; al0 += hv.x*a.x; al1 += hv.x*a.y; ar0 += hv.x*b.x; ar1 += hv.x*b.y;
        a = wl2[k+1]; b = wr2[k+1]; al0 += hv.y*a.x; al1 += hv.y*a.y; ar0 += hv.y*b.x; ar1 += hv.y*b.y;
        a = wl2[k+2]; b = wr2[k+2]; al0 += hv.z*a.x; al1 += hv.z*a.y; ar0 += hv.z*b.x; ar1 += hv.z*b.y;
        a = wl2[k+3]; b = wr2[k+3]; al0 += hv.w*a.x; al1 += hv.w*a.y; ar0 += hv.w*b.x; ar1 += hv.w*b.y;
    }
    *reinterpret_cast<float2*>(xl1 + (size_t)n * 2) = make_float2(al0, al1);
    *reinterpret_cast<float2*>(xr1 + (size_t)n * 2) = make_float2(ar0, ar1);
}

// ---- layer-1 fused: thread per dst; 4-deep pipelined gather, normalize at end
__global__ __launch_bounds__(256) void k_layer1(
    const int* __restrict__ rowst, const int* __restrict__ csr,
    const float* __restrict__ xl1, const float* __restrict__ xr1,
    const float* __restrict__ att1, const float* __restrict__ bias1,
    float* __restrict__ out)
{
    int d = blockIdx.x * 256 + threadIdx.x;
    if (d >= NN) return;
    float2 xr = *reinterpret_cast<const float2*>(xr1 + (size_t)d * 2);
    float A0 = att1[0], A1 = att1[1];
    int rs = rowst[d], re = rowst[d + 1];
    float sum = 0.f, a0 = 0.f, a1 = 0.f;
    int i = rs;
    for (; i + 4 <= re; i += 4) {
        int s0 = csr[i], s1 = csr[i+1], s2 = csr[i+2], s3 = csr[i+3];
        float2 x0 = *reinterpret_cast<const float2*>(xl1 + (size_t)s0 * 2);
        float2 x1 = *reinterpret_cast<const float2*>(xl1 + (size_t)s1 * 2);
        float2 x2 = *reinterpret_cast<const float2*>(xl1 + (size_t)s2 * 2);
        float2 x3 = *reinterpret_cast<const float2*>(xl1 + (size_t)s3 * 2);
        float w0 = __expf(lrelu(x0.x + xr.x) * A0 + lrelu(x0.y + xr.y) * A1);
        float w1 = __expf(lrelu(x1.x + xr.x) * A0 + lrelu(x1.y + xr.y) * A1);
        float w2 = __expf(lrelu(x2.x + xr.x) * A0 + lrelu(x2.y + xr.y) * A1);
        float w3 = __expf(lrelu(x3.x + xr.x) * A0 + lrelu(x3.y + xr.y) * A1);
        sum += w0 + w1 + w2 + w3;
        a0 += w0 * x0.x + w1 * x1.x + w2 * x2.x + w3 * x3.x;
        a1 += w0 * x0.y + w1 * x1.y + w2 * x2.y + w3 * x3.y;
    }
    for (; i < re; ++i) {
        int s = csr[i];
        float2 xs = *reinterpret_cast<const float2*>(xl1 + (size_t)s * 2);
        float wgt = __expf(lrelu(xs.x + xr.x) * A0 + lrelu(xs.y + xr.y) * A1);
        sum += wgt;
        a0 += wgt * xs.x;
        a1 += wgt * xs.y;
    }
    float r = 1.f / (sum + 1e-16f);
    out[(size_t)d * 2]     = a0 * r + bias1[0];
    out[(size_t)d * 2 + 1] = a1 * r + bias1[1];
}

extern "C" void kernel_launch(void* const* d_in, const int* in_sizes, int n_in,
                              void* d_out, int out_size, void* d_ws, size_t ws_size,
                              hipStream_t stream)
{
    const float* x     = (const float*)d_in[0];
    const int*   ei    = (const int*)d_in[1];
    const int*   ts    = (const int*)d_in[2];
    const float* Wt    = (const float*)d_in[3];
    const float* Wl0   = (const float*)d_in[4];
    const float* bl0   = (const float*)d_in[5];
    const float* Wr0   = (const float*)d_in[6];
    const float* br0   = (const float*)d_in[7];
    const float* att0  = (const float*)d_in[8];
    const float* bias0 = (const float*)d_in[9];
    const float* Wl1   = (const float*)d_in[10];
    const float* bl1   = (const float*)d_in[11];
    const float* Wr1   = (const float*)d_in[12];
    const float* br1   = (const float*)d_in[13];
    const float* att1  = (const float*)d_in[14];
    const float* bias1 = (const float*)d_in[15];
    float* out = (float*)d_out;

    char* wsp = (char*)d_ws;
    size_t off = 0;
    auto alloc = [&](size_t bytes) -> void* {
        void* p = wsp + off;
        off += (bytes + 255) & ~(size_t)255;
        return p;
    };
    float* xl0   = (float*)alloc((size_t)NN * D1 * 4);
    float* xr0   = (float*)alloc((size_t)NN * D1 * 4);
    float* h1    = (float*)alloc((size_t)NN * D1 * 4);
    float* xl1   = (float*)alloc((size_t)NN * 2 * 4);
    float* xr1   = (float*)alloc((size_t)NN * 2 * 4);
    int* deg     = (int*)alloc((size_t)NN * 4);
    int* rowst   = (int*)alloc((size_t)(NN + 1) * 4);
    int* cursor  = (int*)alloc((size_t)NN * 4);
    int* csr     = (int*)alloc((size_t)EP * 4);

    hipMemsetAsync(deg, 0, (size_t)NN * 4, stream);

    k_gemm0<<<512, 256, 0, stream>>>(x, ts, Wt, Wl0, bl0, Wr0, br0, xl0, xr0);
    k_deg<<<(EP + 255) / 256, 256, 0, stream>>>(ei, deg);
    k_scan<<<1, 1024, 0, stream>>>(deg, rowst, cursor);
    k_scatter<<<(EP + 255) / 256, 256, 0, stream>>>(ei, cursor, csr);
    k_agg0<<<(NN + 3) / 4, 256, 0, stream>>>(rowst, csr, xl0, xr0, att0, bias0, h1);
    k_gemm1<<<(NN + 255) / 256, 256, 0, stream>>>(h1, Wl1, bl1, Wr1, br1, xl1, xr1);
    k_layer1<<<(NN + 255) / 256, 256, 0, stream>>>(rowst, csr, xl1, xr1, att1, bias1, out);
}

// Round 4
// 303.873 us; speedup vs baseline: 2.3978x; 1.6961x over previous
//
#include <hip/hip_runtime.h>

#define NN 50000
#define NE 1600000
#define EP (NE + NN)          // edges + self loops = 1,650,000
#define INC 64
#define TDIM 32
#define INDIM 96
#define D1 128
#define NEG 0.2f

// bucketed CSR build: 16 dst-nodes per bucket
#define NB 3125               // NN / 16 exactly
#define CAP 768               // per-bucket staging capacity (mean 528, 10σ headroom)
#define PADC 16               // bucket counter padding (one per 64B line)

__device__ __forceinline__ float lrelu(float v) { return v > 0.f ? v : NEG * v; }

// ---- GEMM0: h=[x | W_time[ts]];  xl0 = h@Wl0+bl0 ; xr0 = h@Wr0+br0  (cols in regs)
__global__ __launch_bounds__(256) void k_gemm0(
    const float* __restrict__ x, const int* __restrict__ ts,
    const float* __restrict__ Wt,
    const float* __restrict__ Wl, const float* __restrict__ bl,
    const float* __restrict__ Wr, const float* __restrict__ br,
    float* __restrict__ xl0, float* __restrict__ xr0)
{
    const int t = threadIdx.x;
    const int col = t & 127;
    const bool isR = (t >= 128);
    const float* __restrict__ W = isR ? Wr : Wl;
    float wreg[INDIM];
#pragma unroll
    for (int k = 0; k < INDIM; ++k) wreg[k] = W[k * D1 + col];
    const float bias = isR ? br[col] : bl[col];
    float* __restrict__ outp = isR ? xr0 : xl0;

    __shared__ float hs[8][INDIM];
    const int tiles = (NN + 7) / 8;
    for (int tile = blockIdx.x; tile < tiles; tile += gridDim.x) {
        const int base = tile * 8;
        __syncthreads();
#pragma unroll
        for (int j = 0; j < 3; ++j) {
            int flat = j * 256 + t;        // 0..767 covers 8*96
            int nd = flat / INDIM;
            int k = flat - nd * INDIM;
            int n = base + nd;
            float v = 0.f;
            if (n < NN)
                v = (k < INC) ? x[(size_t)n * INC + k]
                              : Wt[(size_t)ts[n] * TDIM + (k - INC)];
            hs[nd][k] = v;
        }
        __syncthreads();
#pragma unroll
        for (int nd = 0; nd < 8; ++nd) {
            int n = base + nd;
            if (n >= NN) break;
            const float4* hp = reinterpret_cast<const float4*>(&hs[nd][0]);
            float acc = bias;
#pragma unroll
            for (int k4 = 0; k4 < INDIM / 4; ++k4) {
                float4 hv = hp[k4];
                acc += wreg[4*k4+0]*hv.x + wreg[4*k4+1]*hv.y
                     + wreg[4*k4+2]*hv.z + wreg[4*k4+3]*hv.w;
            }
            outp[(size_t)n * D1 + col] = acc;
        }
    }
}

// ================= new bucketed CSR build =================

// ---- pass A: bin edges by dst-bucket; packed (src | dst<<16) appended at bucket tail
__global__ __launch_bounds__(256) void k_bin(
    const int* __restrict__ ei, int* __restrict__ bcnt, unsigned* __restrict__ stage)
{
    int e = blockIdx.x * 256 + threadIdx.x;
    if (e >= EP) return;
    int s, d;
    if (e < NE) { s = ei[e]; d = ei[NE + e]; }
    else        { s = e - NE; d = s; }
    int b = d >> 4;
    int pos = atomicAdd(&bcnt[b * PADC], 1);
    if (pos < CAP) stage[(size_t)b * CAP + pos] = (unsigned)s | ((unsigned)d << 16);
}

// ---- scan bucket counts -> bucket bases
__global__ __launch_bounds__(1024) void k_bscan(
    const int* __restrict__ bcnt, int* __restrict__ bbase, int* __restrict__ rowst)
{
    __shared__ int sums[1024];
    const int t = threadIdx.x;
    const int chunk = (NB + 1023) / 1024;   // 4
    int loc[4];
    int s = 0;
    for (int i = 0; i < chunk; ++i) {
        int idx = t * chunk + i;
        int v = (idx < NB) ? min(bcnt[idx * PADC], CAP) : 0;
        loc[i] = s;
        s += v;
    }
    sums[t] = s;
    __syncthreads();
    for (int off = 1; off < 1024; off <<= 1) {
        int add = (t >= off) ? sums[t - off] : 0;
        __syncthreads();
        sums[t] += add;
        __syncthreads();
    }
    int run = sums[t] - s;   // exclusive prefix over threads
    for (int i = 0; i < chunk; ++i) {
        int idx = t * chunk + i;
        if (idx < NB) bbase[idx] = run + loc[i];
    }
    if (t == 0) rowst[NN] = EP;
}

// ---- pass B: per bucket: LDS hist over 16 dsts -> rowst; scatter src into 2KB csr window
__global__ __launch_bounds__(256) void k_build(
    const int* __restrict__ bcnt, const int* __restrict__ bbase,
    const unsigned* __restrict__ stage,
    int* __restrict__ rowst, int* __restrict__ csr)
{
    const int b = blockIdx.x;
    const int t = threadIdx.x;
    const int cnt = min(bcnt[b * PADC], CAP);
    const int base = bbase[b];
    __shared__ int hist[16], curs[16];
    if (t < 16) hist[t] = 0;
    __syncthreads();
    unsigned pk[3];                   // CAP/256 = 3 max per thread
    int np = 0;
    for (int i = t; i < cnt; i += 256) {
        unsigned v = stage[(size_t)b * CAP + i];
        pk[np++] = v;
        atomicAdd(&hist[(v >> 16) & 15], 1);
    }
    __syncthreads();
    if (t < 16) {
        int excl = 0;
        for (int j = 0; j < t; ++j) excl += hist[j];
        rowst[b * 16 + t] = base + excl;
        curs[t] = excl;
    }
    __syncthreads();
    for (int i = 0; i < np; ++i) {
        unsigned v = pk[i];
        int pos = atomicAdd(&curs[(v >> 16) & 15], 1);
        csr[base + pos] = (int)(v & 0xFFFFu);
    }
}

// ================= fallback (old) CSR build =================

__global__ __launch_bounds__(256) void k_deg(const int* __restrict__ ei, int* __restrict__ deg)
{
    int e = blockIdx.x * 256 + threadIdx.x;
    if (e >= EP) return;
    int d = (e < NE) ? ei[NE + e] : (e - NE);
    atomicAdd(&deg[d], 1);
}

__global__ __launch_bounds__(1024) void k_scan(
    const int* __restrict__ deg, int* __restrict__ rowst, int* __restrict__ cursor)
{
    __shared__ int sums[1024];
    const int t = threadIdx.x;
    const int chunk = (NN + 1023) / 1024;   // 49
    const int base = t * chunk;
    int s = 0;
    for (int i = 0; i < chunk; ++i) {
        int idx = base + i;
        if (idx < NN) s += deg[idx];
    }
    sums[t] = s;
    __syncthreads();
    for (int off = 1; off < 1024; off <<= 1) {
        int add = (t >= off) ? sums[t - off] : 0;
        __syncthreads();
        sums[t] += add;
        __syncthreads();
    }
    int run = sums[t] - s;
    for (int i = 0; i < chunk; ++i) {
        int idx = base + i;
        if (idx < NN) {
            rowst[idx] = run;
            cursor[idx] = run;
            run += deg[idx];
        }
    }
    if (t == 0) rowst[NN] = EP;
}

__global__ __launch_bounds__(256) void k_scatter(
    const int* __restrict__ ei, int* __restrict__ cursor, int* __restrict__ csr)
{
    int e = blockIdx.x * 256 + threadIdx.x;
    if (e >= EP) return;
    int d, s;
    if (e < NE) { d = ei[NE + e]; s = ei[e]; }
    else        { d = e - NE;     s = e - NE; }
    int pos = atomicAdd(&cursor[d], 1);
    csr[pos] = s;
}

// ================= aggregation / dense =================

// ---- layer-0 fused: per-dst wave; 8-deep pipelined gather + softmax-free norm
__global__ __launch_bounds__(256) void k_agg0(
    const int* __restrict__ rowst, const int* __restrict__ csr,
    const float* __restrict__ xl0, const float* __restrict__ xr0,
    const float* __restrict__ att0, const float* __restrict__ bias0,
    float* __restrict__ h1)
{
    const int d = (blockIdx.x * 256 + threadIdx.x) >> 6;
    const int lane = threadIdx.x & 63;
    if (d >= NN) return;
    const int c = lane * 2;                 // lane owns channels c, c+1 (head = lane/16)
    float2 xr = *reinterpret_cast<const float2*>(xr0 + (size_t)d * D1 + c);
    float2 at = *reinterpret_cast<const float2*>(att0 + c);
    const int rs = rowst[d], re = rowst[d + 1];
    float accx = 0.f, accy = 0.f, wsum = 0.f;

    int i = rs;
    for (; i + 8 <= re; i += 8) {
        int s[8];
#pragma unroll
        for (int j = 0; j < 8; ++j) s[j] = csr[i + j];
        float2 xs[8];
#pragma unroll
        for (int j = 0; j < 8; ++j)
            xs[j] = *reinterpret_cast<const float2*>(xl0 + (size_t)s[j] * D1 + c);
#pragma unroll
        for (int j = 0; j < 8; ++j) {
            float p = lrelu(xs[j].x + xr.x) * at.x + lrelu(xs[j].y + xr.y) * at.y;
            p += __shfl_xor(p, 1);
            p += __shfl_xor(p, 2);
            p += __shfl_xor(p, 4);
            p += __shfl_xor(p, 8);          // 16-lane (one head) reduction
            float wgt = __expf(p);
            wsum += wgt;
            accx += wgt * xs[j].x;
            accy += wgt * xs[j].y;
        }
    }
    for (; i < re; ++i) {
        int s = csr[i];
        float2 xs = *reinterpret_cast<const float2*>(xl0 + (size_t)s * D1 + c);
        float p = lrelu(xs.x + xr.x) * at.x + lrelu(xs.y + xr.y) * at.y;
        p += __shfl_xor(p, 1);
        p += __shfl_xor(p, 2);
        p += __shfl_xor(p, 4);
        p += __shfl_xor(p, 8);
        float wgt = __expf(p);
        wsum += wgt;
        accx += wgt * xs.x;
        accy += wgt * xs.y;
    }
    float r = 1.f / (wsum + 1e-16f);
    h1[(size_t)d * D1 + c]     = fmaxf(accx * r + bias0[c], 0.f);
    h1[(size_t)d * D1 + c + 1] = fmaxf(accy * r + bias0[c + 1], 0.f);
}

// ---- GEMM1: xl1 = h1@Wl1+bl1 ; xr1 = h1@Wr1+br1   (thread per node)
__global__ __launch_bounds__(256) void k_gemm1(
    const float* __restrict__ h1,
    const float* __restrict__ Wl, const float* __restrict__ bl,
    const float* __restrict__ Wr, const float* __restrict__ br,
    float* __restrict__ xl1, float* __restrict__ xr1)
{
    __shared__ float wls[D1 * 2], wrs[D1 * 2];
    const int t = threadIdx.x;
    wls[t] = Wl[t]; wrs[t] = Wr[t];
    __syncthreads();
    int n = blockIdx.x * 256 + t;
    if (n >= NN) return;
    float al0 = bl[0], al1 = bl[1], ar0 = br[0], ar1 = br[1];
    const float4* hp = reinterpret_cast<const float4*>(h1 + (size_t)n * D1);
    const float2* wl2 = reinterpret_cast<const float2*>(wls);
    const float2* wr2 = reinterpret_cast<const float2*>(wrs);
#pragma unroll
    for (int k4 = 0; k4 < D1 / 4; ++k4) {
        float4 hv = hp[k4];
        int k = k4 * 4;
        float2 a, b;
        a = wl2[k+0]; b = wr2[k+0]; al0 += hv.x*a.x; al1 += hv.x*a.y; ar0 += hv.x*b.x; ar1 += hv.x*b.y;
        a = wl2[k+1]; b = wr2[k+1]; al0 += hv.y*a.x; al1 += hv.y*a.y; ar0 += hv.y*b.x; ar1 += hv.y*b.y;
        a = wl2[k+2]; b = wr2[k+2]; al0 += hv.z*a.x; al1 += hv.z*a.y; ar0 += hv.z*b.x; ar1 += hv.z*b.y;
        a = wl2[k+3]; b = wr2[k+3]; al0 += hv.w*a.x; al1 += hv.w*a.y; ar0 += hv.w*b.x; ar1 += hv.w*b.y;
    }
    *reinterpret_cast<float2*>(xl1 + (size_t)n * 2) = make_float2(al0, al1);
    *reinterpret_cast<float2*>(xr1 + (size_t)n * 2) = make_float2(ar0, ar1);
}

// ---- layer-1 fused: thread per dst; 4-deep pipelined gather, normalize at end
__global__ __launch_bounds__(256) void k_layer1(
    const int* __restrict__ rowst, const int* __restrict__ csr,
    const float* __restrict__ xl1, const float* __restrict__ xr1,
    const float* __restrict__ att1, const float* __restrict__ bias1,
    float* __restrict__ out)
{
    int d = blockIdx.x * 256 + threadIdx.x;
    if (d >= NN) return;
    float2 xr = *reinterpret_cast<const float2*>(xr1 + (size_t)d * 2);
    float A0 = att1[0], A1 = att1[1];
    int rs = rowst[d], re = rowst[d + 1];
    float sum = 0.f, a0 = 0.f, a1 = 0.f;
    int i = rs;
    for (; i + 4 <= re; i += 4) {
        int s0 = csr[i], s1 = csr[i+1], s2 = csr[i+2], s3 = csr[i+3];
        float2 x0 = *reinterpret_cast<const float2*>(xl1 + (size_t)s0 * 2);
        float2 x1 = *reinterpret_cast<const float2*>(xl1 + (size_t)s1 * 2);
        float2 x2 = *reinterpret_cast<const float2*>(xl1 + (size_t)s2 * 2);
        float2 x3 = *reinterpret_cast<const float2*>(xl1 + (size_t)s3 * 2);
        float w0 = __expf(lrelu(x0.x + xr.x) * A0 + lrelu(x0.y + xr.y) * A1);
        float w1 = __expf(lrelu(x1.x + xr.x) * A0 + lrelu(x1.y + xr.y) * A1);
        float w2 = __expf(lrelu(x2.x + xr.x) * A0 + lrelu(x2.y + xr.y) * A1);
        float w3 = __expf(lrelu(x3.x + xr.x) * A0 + lrelu(x3.y + xr.y) * A1);
        sum += w0 + w1 + w2 + w3;
        a0 += w0 * x0.x + w1 * x1.x + w2 * x2.x + w3 * x3.x;
        a1 += w0 * x0.y + w1 * x1.y + w2 * x2.y + w3 * x3.y;
    }
    for (; i < re; ++i) {
        int s = csr[i];
        float2 xs = *reinterpret_cast<const float2*>(xl1 + (size_t)s * 2);
        float wgt = __expf(lrelu(xs.x + xr.x) * A0 + lrelu(xs.y + xr.y) * A1);
        sum += wgt;
        a0 += wgt * xs.x;
        a1 += wgt * xs.y;
    }
    float r = 1.f / (sum + 1e-16f);
    out[(size_t)d * 2]     = a0 * r + bias1[0];
    out[(size_t)d * 2 + 1] = a1 * r + bias1[1];
}

extern "C" void kernel_launch(void* const* d_in, const int* in_sizes, int n_in,
                              void* d_out, int out_size, void* d_ws, size_t ws_size,
                              hipStream_t stream)
{
    const float* x     = (const float*)d_in[0];
    const int*   ei    = (const int*)d_in[1];
    const int*   ts    = (const int*)d_in[2];
    const float* Wt    = (const float*)d_in[3];
    const float* Wl0   = (const float*)d_in[4];
    const float* bl0   = (const float*)d_in[5];
    const float* Wr0   = (const float*)d_in[6];
    const float* br0   = (const float*)d_in[7];
    const float* att0  = (const float*)d_in[8];
    const float* bias0 = (const float*)d_in[9];
    const float* Wl1   = (const float*)d_in[10];
    const float* bl1   = (const float*)d_in[11];
    const float* Wr1   = (const float*)d_in[12];
    const float* br1   = (const float*)d_in[13];
    const float* att1  = (const float*)d_in[14];
    const float* bias1 = (const float*)d_in[15];
    float* out = (float*)d_out;

    char* wsp = (char*)d_ws;
    size_t off = 0;
    auto alloc = [&](size_t bytes) -> void* {
        void* p = wsp + off;
        off += (bytes + 255) & ~(size_t)255;
        return p;
    };
    float* xl0   = (float*)alloc((size_t)NN * D1 * 4);
    float* xr0   = (float*)alloc((size_t)NN * D1 * 4);
    float* h1    = (float*)alloc((size_t)NN * D1 * 4);
    float* xl1   = (float*)alloc((size_t)NN * 2 * 4);
    float* xr1   = (float*)alloc((size_t)NN * 2 * 4);
    int* rowst   = (int*)alloc((size_t)(NN + 1) * 4);
    int* csr     = (int*)alloc((size_t)EP * 4);
    size_t base_need = off;

    // new-path scratch
    int* bcnt        = (int*)alloc((size_t)NB * PADC * 4);
    int* bbase       = (int*)alloc((size_t)NB * 4);
    unsigned* stage  = (unsigned*)alloc((size_t)NB * CAP * 4);
    size_t new_need = off;

    k_gemm0<<<512, 256, 0, stream>>>(x, ts, Wt, Wl0, bl0, Wr0, br0, xl0, xr0);

    if (ws_size >= new_need) {
        hipMemsetAsync(bcnt, 0, (size_t)NB * PADC * 4, stream);
        k_bin<<<(EP + 255) / 256, 256, 0, stream>>>(ei, bcnt, stage);
        k_bscan<<<1, 1024, 0, stream>>>(bcnt, bbase, rowst);
        k_build<<<NB, 256, 0, stream>>>(bcnt, bbase, stage, rowst, csr);
    } else {
        // fallback: old build (reuse new-path area if it fits, else after csr)
        size_t off2 = base_need;
        auto alloc2 = [&](size_t bytes) -> void* {
            void* p = wsp + off2;
            off2 += (bytes + 255) & ~(size_t)255;
            return p;
        };
        int* deg    = (int*)alloc2((size_t)NN * 4);
        int* cursor = (int*)alloc2((size_t)NN * 4);
        hipMemsetAsync(deg, 0, (size_t)NN * 4, stream);
        k_deg<<<(EP + 255) / 256, 256, 0, stream>>>(ei, deg);
        k_scan<<<1, 1024, 0, stream>>>(deg, rowst, cursor);
        k_scatter<<<(EP + 255) / 256, 256, 0, stream>>>(ei, cursor, csr);
    }

    k_agg0<<<(NN + 3) / 4, 256, 0, stream>>>(rowst, csr, xl0, xr0, att0, bias0, h1);
    k_gemm1<<<(NN + 255) / 256, 256, 0, stream>>>(h1, Wl1, bl1, Wr1, br1, xl1, xr1);
    k_layer1<<<(NN + 255) / 256, 256, 0, stream>>>(rowst, csr, xl1, xr1, att1, bias1, out);
}

// Round 8
// 283.327 us; speedup vs baseline: 2.5717x; 1.0725x over previous
//
#include <hip/hip_runtime.h>
#include <hip/hip_fp16.h>

#define NN 50000
#define NE 1600000
#define EP (NE + NN)          // edges + self loops = 1,650,000
#define INC 64
#define TDIM 32
#define INDIM 96
#define D1 128
#define NEG 0.2f

// bucketed CSR build: 16 dst-nodes per bucket
#define NB 3125               // NN / 16 exactly
#define CAP 768               // per-bucket staging capacity (mean 528, 10σ headroom)
#define PADC 16               // bucket counter padding (one per 64B line)

__device__ __forceinline__ float lrelu(float v) { return v > 0.f ? v : NEG * v; }

// ---- GEMM0: h=[x | W_time[ts]];  xl0 = h@Wl0+bl0 ; xr0 = h@Wr0+br0  (fp16 out)
__global__ __launch_bounds__(256) void k_gemm0(
    const float* __restrict__ x, const int* __restrict__ ts,
    const float* __restrict__ Wt,
    const float* __restrict__ Wl, const float* __restrict__ bl,
    const float* __restrict__ Wr, const float* __restrict__ br,
    __half* __restrict__ xl0, __half* __restrict__ xr0)
{
    const int t = threadIdx.x;
    const int col = t & 127;
    const bool isR = (t >= 128);
    const float* __restrict__ W = isR ? Wr : Wl;
    float wreg[INDIM];
#pragma unroll
    for (int k = 0; k < INDIM; ++k) wreg[k] = W[k * D1 + col];
    const float bias = isR ? br[col] : bl[col];
    __half* __restrict__ outp = isR ? xr0 : xl0;

    __shared__ float hs[8][INDIM];
    const int tiles = (NN + 7) / 8;
    for (int tile = blockIdx.x; tile < tiles; tile += gridDim.x) {
        const int base = tile * 8;
        __syncthreads();
#pragma unroll
        for (int j = 0; j < 3; ++j) {
            int flat = j * 256 + t;        // 0..767 covers 8*96
            int nd = flat / INDIM;
            int k = flat - nd * INDIM;
            int n = base + nd;
            float v = 0.f;
            if (n < NN)
                v = (k < INC) ? x[(size_t)n * INC + k]
                              : Wt[(size_t)ts[n] * TDIM + (k - INC)];
            hs[nd][k] = v;
        }
        __syncthreads();
#pragma unroll
        for (int nd = 0; nd < 8; ++nd) {
            int n = base + nd;
            if (n >= NN) break;
            const float4* hp = reinterpret_cast<const float4*>(&hs[nd][0]);
            float acc = bias;
#pragma unroll
            for (int k4 = 0; k4 < INDIM / 4; ++k4) {
                float4 hv = hp[k4];
                acc += wreg[4*k4+0]*hv.x + wreg[4*k4+1]*hv.y
                     + wreg[4*k4+2]*hv.z + wreg[4*k4+3]*hv.w;
            }
            outp[(size_t)n * D1 + col] = __float2half(acc);
        }
    }
}

// ================= bucketed CSR build =================

// ---- pass A: bin edges by dst-bucket; packed (src | dst<<16) appended at bucket tail
__global__ __launch_bounds__(256) void k_bin(
    const int* __restrict__ ei, int* __restrict__ bcnt, unsigned* __restrict__ stage)
{
    int e = blockIdx.x * 256 + threadIdx.x;
    if (e >= EP) return;
    int s, d;
    if (e < NE) { s = ei[e]; d = ei[NE + e]; }
    else        { s = e - NE; d = s; }
    int b = d >> 4;
    int pos = atomicAdd(&bcnt[b * PADC], 1);
    if (pos < CAP) stage[(size_t)b * CAP + pos] = (unsigned)s | ((unsigned)d << 16);
}

// ---- scan bucket counts -> bucket bases
__global__ __launch_bounds__(1024) void k_bscan(
    const int* __restrict__ bcnt, int* __restrict__ bbase, int* __restrict__ rowst)
{
    __shared__ int sums[1024];
    const int t = threadIdx.x;
    const int chunk = (NB + 1023) / 1024;   // 4
    int loc[4];
    int s = 0;
    for (int i = 0; i < chunk; ++i) {
        int idx = t * chunk + i;
        int v = (idx < NB) ? min(bcnt[idx * PADC], CAP) : 0;
        loc[i] = s;
        s += v;
    }
    sums[t] = s;
    __syncthreads();
    for (int off = 1; off < 1024; off <<= 1) {
        int add = (t >= off) ? sums[t - off] : 0;
        __syncthreads();
        sums[t] += add;
        __syncthreads();
    }
    int run = sums[t] - s;   // exclusive prefix over threads
    for (int i = 0; i < chunk; ++i) {
        int idx = t * chunk + i;
        if (idx < NB) bbase[idx] = run + loc[i];
    }
    if (t == 0) rowst[NN] = EP;
}

// ---- pass B: per bucket: LDS hist over 16 dsts -> rowst; scatter src (u16) into csr window
__global__ __launch_bounds__(256) void k_build(
    const int* __restrict__ bcnt, const int* __restrict__ bbase,
    const unsigned* __restrict__ stage,
    int* __restrict__ rowst, unsigned short* __restrict__ csr)
{
    const int b = blockIdx.x;
    const int t = threadIdx.x;
    const int cnt = min(bcnt[b * PADC], CAP);
    const int base = bbase[b];
    __shared__ int hist[16], curs[16];
    if (t < 16) hist[t] = 0;
    __syncthreads();
    unsigned pk[3];                   // CAP/256 = 3 max per thread
    int np = 0;
    for (int i = t; i < cnt; i += 256) {
        unsigned v = stage[(size_t)b * CAP + i];
        pk[np++] = v;
        atomicAdd(&hist[(v >> 16) & 15], 1);
    }
    __syncthreads();
    if (t < 16) {
        int excl = 0;
        for (int j = 0; j < t; ++j) excl += hist[j];
        rowst[b * 16 + t] = base + excl;
        curs[t] = excl;
    }
    __syncthreads();
    for (int i = 0; i < np; ++i) {
        unsigned v = pk[i];
        int pos = atomicAdd(&curs[(v >> 16) & 15], 1);
        csr[base + pos] = (unsigned short)(v & 0xFFFFu);
    }
}

// ================= aggregation / dense =================

// ---- layer-0 fused: per-dst wave; 8-deep pipelined fp16 gather + softmax-free norm
__global__ __launch_bounds__(256) void k_agg0(
    const int* __restrict__ rowst, const unsigned short* __restrict__ csr,
    const __half* __restrict__ xl0, const __half* __restrict__ xr0,
    const float* __restrict__ att0, const float* __restrict__ bias0,
    float* __restrict__ h1)
{
    const int d = (blockIdx.x * 256 + threadIdx.x) >> 6;
    const int lane = threadIdx.x & 63;
    if (d >= NN) return;
    const int c = lane * 2;                 // lane owns channels c, c+1 (head = lane/16)
    float2 xr = __half22float2(*reinterpret_cast<const __half2*>(xr0 + (size_t)d * D1 + c));
    float2 at = *reinterpret_cast<const float2*>(att0 + c);
    const int rs = rowst[d], re = rowst[d + 1];
    float accx = 0.f, accy = 0.f, wsum = 0.f;

    int i = rs;
    for (; i + 8 <= re; i += 8) {
        int s[8];
#pragma unroll
        for (int j = 0; j < 8; ++j) s[j] = csr[i + j];
        float2 xs[8];
#pragma unroll
        for (int j = 0; j < 8; ++j)
            xs[j] = __half22float2(*reinterpret_cast<const __half2*>(xl0 + (size_t)s[j] * D1 + c));
#pragma unroll
        for (int j = 0; j < 8; ++j) {
            float p = lrelu(xs[j].x + xr.x) * at.x + lrelu(xs[j].y + xr.y) * at.y;
            p += __shfl_xor(p, 1);
            p += __shfl_xor(p, 2);
            p += __shfl_xor(p, 4);
            p += __shfl_xor(p, 8);          // 16-lane (one head) reduction
            float wgt = __expf(p);
            wsum += wgt;
            accx += wgt * xs[j].x;
            accy += wgt * xs[j].y;
        }
    }
    for (; i < re; ++i) {
        int s = csr[i];
        float2 xs = __half22float2(*reinterpret_cast<const __half2*>(xl0 + (size_t)s * D1 + c));
        float p = lrelu(xs.x + xr.x) * at.x + lrelu(xs.y + xr.y) * at.y;
        p += __shfl_xor(p, 1);
        p += __shfl_xor(p, 2);
        p += __shfl_xor(p, 4);
        p += __shfl_xor(p, 8);
        float wgt = __expf(p);
        wsum += wgt;
        accx += wgt * xs.x;
        accy += wgt * xs.y;
    }
    float r = 1.f / (wsum + 1e-16f);
    h1[(size_t)d * D1 + c]     = fmaxf(accx * r + bias0[c], 0.f);
    h1[(size_t)d * D1 + c + 1] = fmaxf(accy * r + bias0[c + 1], 0.f);
}

// ---- GEMM1: xl1 = h1@Wl1+bl1 ; xr1 = h1@Wr1+br1   (thread per node)
__global__ __launch_bounds__(256) void k_gemm1(
    const float* __restrict__ h1,
    const float* __restrict__ Wl, const float* __restrict__ bl,
    const float* __restrict__ Wr, const float* __restrict__ br,
    float* __restrict__ xl1, float* __restrict__ xr1)
{
    __shared__ float wls[D1 * 2], wrs[D1 * 2];
    const int t = threadIdx.x;
    wls[t] = Wl[t]; wrs[t] = Wr[t];
    __syncthreads();
    int n = blockIdx.x * 256 + t;
    if (n >= NN) return;
    float al0 = bl[0], al1 = bl[1], ar0 = br[0], ar1 = br[1];
    const float4* hp = reinterpret_cast<const float4*>(h1 + (size_t)n * D1);
    const float2* wl2 = reinterpret_cast<const float2*>(wls);
    const float2* wr2 = reinterpret_cast<const float2*>(wrs);
#pragma unroll
    for (int k4 = 0; k4 < D1 / 4; ++k4) {
        float4 hv = hp[k4];
        int k = k4 * 4;
        float2 a, b;
        a = wl2[k+0]; b = wr2[k+0]; al0 += hv.x*a.x; al1 += hv.x*a.y; ar0 += hv.x*b.x; ar1 += hv.x*b.y;
        a = wl2[k+1]; b = wr2[k+1]; al0 += hv.y*a.x; al1 += hv.y*a.y; ar0 += hv.y*b.x; ar1 += hv.y*b.y;
        a = wl2[k+2]; b = wr2[k+2]; al0 += hv.z*a.x; al1 += hv.z*a.y; ar0 += hv.z*b.x; ar1 += hv.z*b.y;
        a = wl2[k+3]; b = wr2[k+3]; al0 += hv.w*a.x; al1 += hv.w*a.y; ar0 += hv.w*b.x; ar1 += hv.w*b.y;
    }
    *reinterpret_cast<float2*>(xl1 + (size_t)n * 2) = make_float2(al0, al1);
    *reinterpret_cast<float2*>(xr1 + (size_t)n * 2) = make_float2(ar0, ar1);
}

// ---- layer-1 fused: thread per dst; 4-deep pipelined gather, normalize at end
__global__ __launch_bounds__(256) void k_layer1(
    const int* __restrict__ rowst, const unsigned short* __restrict__ csr,
    const float* __restrict__ xl1, const float* __restrict__ xr1,
    const float* __restrict__ att1, const float* __restrict__ bias1,
    float* __restrict__ out)
{
    int d = blockIdx.x * 256 + threadIdx.x;
    if (d >= NN) return;
    float2 xr = *reinterpret_cast<const float2*>(xr1 + (size_t)d * 2);
    float A0 = att1[0], A1 = att1[1];
    int rs = rowst[d], re = rowst[d + 1];
    float sum = 0.f, a0 = 0.f, a1 = 0.f;
    int i = rs;
    for (; i + 4 <= re; i += 4) {
        int s0 = csr[i], s1 = csr[i+1], s2 = csr[i+2], s3 = csr[i+3];
        float2 x0 = *reinterpret_cast<const float2*>(xl1 + (size_t)s0 * 2);
        float2 x1 = *reinterpret_cast<const float2*>(xl1 + (size_t)s1 * 2);
        float2 x2 = *reinterpret_cast<const float2*>(xl1 + (size_t)s2 * 2);
        float2 x3 = *reinterpret_cast<const float2*>(xl1 + (size_t)s3 * 2);
        float w0 = __expf(lrelu(x0.x + xr.x) * A0 + lrelu(x0.y + xr.y) * A1);
        float w1 = __expf(lrelu(x1.x + xr.x) * A0 + lrelu(x1.y + xr.y) * A1);
        float w2 = __expf(lrelu(x2.x + xr.x) * A0 + lrelu(x2.y + xr.y) * A1);
        float w3 = __expf(lrelu(x3.x + xr.x) * A0 + lrelu(x3.y + xr.y) * A1);
        sum += w0 + w1 + w2 + w3;
        a0 += w0 * x0.x + w1 * x1.x + w2 * x2.x + w3 * x3.x;
        a1 += w0 * x0.y + w1 * x1.y + w2 * x2.y + w3 * x3.y;
    }
    for (; i < re; ++i) {
        int s = csr[i];
        float2 xs = *reinterpret_cast<const float2*>(xl1 + (size_t)s * 2);
        float wgt = __expf(lrelu(xs.x + xr.x) * A0 + lrelu(xs.y + xr.y) * A1);
        sum += wgt;
        a0 += wgt * xs.x;
        a1 += wgt * xs.y;
    }
    float r = 1.f / (sum + 1e-16f);
    out[(size_t)d * 2]     = a0 * r + bias1[0];
    out[(size_t)d * 2 + 1] = a1 * r + bias1[1];
}

extern "C" void kernel_launch(void* const* d_in, const int* in_sizes, int n_in,
                              void* d_out, int out_size, void* d_ws, size_t ws_size,
                              hipStream_t stream)
{
    const float* x     = (const float*)d_in[0];
    const int*   ei    = (const int*)d_in[1];
    const int*   ts    = (const int*)d_in[2];
    const float* Wt    = (const float*)d_in[3];
    const float* Wl0   = (const float*)d_in[4];
    const float* bl0   = (const float*)d_in[5];
    const float* Wr0   = (const float*)d_in[6];
    const float* br0   = (const float*)d_in[7];
    const float* att0  = (const float*)d_in[8];
    const float* bias0 = (const float*)d_in[9];
    const float* Wl1   = (const float*)d_in[10];
    const float* bl1   = (const float*)d_in[11];
    const float* Wr1   = (const float*)d_in[12];
    const float* br1   = (const float*)d_in[13];
    const float* att1  = (const float*)d_in[14];
    const float* bias1 = (const float*)d_in[15];
    float* out = (float*)d_out;

    char* wsp = (char*)d_ws;
    size_t off = 0;
    auto alloc = [&](size_t bytes) -> void* {
        void* p = wsp + off;
        off += (bytes + 255) & ~(size_t)255;
        return p;
    };
    __half* xl0  = (__half*)alloc((size_t)NN * D1 * 2);
    __half* xr0  = (__half*)alloc((size_t)NN * D1 * 2);
    float* h1    = (float*)alloc((size_t)NN * D1 * 4);
    float* xl1   = (float*)alloc((size_t)NN * 2 * 4);
    float* xr1   = (float*)alloc((size_t)NN * 2 * 4);
    int* rowst   = (int*)alloc((size_t)(NN + 1) * 4);
    unsigned short* csr = (unsigned short*)alloc((size_t)EP * 2);
    int* bcnt        = (int*)alloc((size_t)NB * PADC * 4);
    int* bbase       = (int*)alloc((size_t)NB * 4);
    unsigned* stage  = (unsigned*)alloc((size_t)NB * CAP * 4);

    k_gemm0<<<512, 256, 0, stream>>>(x, ts, Wt, Wl0, bl0, Wr0, br0, xl0, xr0);

    hipMemsetAsync(bcnt, 0, (size_t)NB * PADC * 4, stream);
    k_bin<<<(EP + 255) / 256, 256, 0, stream>>>(ei, bcnt, stage);
    k_bscan<<<1, 1024, 0, stream>>>(bcnt, bbase, rowst);
    k_build<<<NB, 256, 0, stream>>>(bcnt, bbase, stage, rowst, csr);

    k_agg0<<<(NN + 3) / 4, 256, 0, stream>>>(rowst, csr, xl0, xr0, att0, bias0, h1);
    k_gemm1<<<(NN + 255) / 256, 256, 0, stream>>>(h1, Wl1, bl1, Wr1, br1, xl1, xr1);
    k_layer1<<<(NN + 255) / 256, 256, 0, stream>>>(rowst, csr, xl1, xr1, att1, bias1, out);
}

// Round 10
// 256.627 us; speedup vs baseline: 2.8392x; 1.1040x over previous
//
#include <hip/hip_runtime.h>
#include <hip/hip_fp16.h>

#define NN 50000
#define NE 1600000
#define EP (NE + NN)          // edges + self loops = 1,650,000
#define INC 64
#define TDIM 32
#define INDIM 96
#define D1 128
#define NEG 0.2f

// bucketed CSR build: 16 dst-nodes per bucket
#define NB 3125               // NN / 16 exactly
#define CAP 768               // per-bucket staging capacity (mean 528, 10σ headroom)
#define PADC 16               // bucket counter padding (one per 64B line)

typedef _Float16 h2v __attribute__((ext_vector_type(2)));
union H2U { unsigned u; __half2 h; h2v v; };

__device__ __forceinline__ float lrelu(float v) { return v > 0.f ? v : NEG * v; }

// ---- GEMM0: h=[x | W_time[ts]];  xl0 = h@Wl0+bl0 ; xr0 = h@Wr0+br0  (fp16 out)
__global__ __launch_bounds__(256) void k_gemm0(
    const float* __restrict__ x, const int* __restrict__ ts,
    const float* __restrict__ Wt,
    const float* __restrict__ Wl, const float* __restrict__ bl,
    const float* __restrict__ Wr, const float* __restrict__ br,
    __half* __restrict__ xl0, __half* __restrict__ xr0)
{
    const int t = threadIdx.x;
    const int col = t & 127;
    const bool isR = (t >= 128);
    const float* __restrict__ W = isR ? Wr : Wl;
    float wreg[INDIM];
#pragma unroll
    for (int k = 0; k < INDIM; ++k) wreg[k] = W[k * D1 + col];
    const float bias = isR ? br[col] : bl[col];
    __half* __restrict__ outp = isR ? xr0 : xl0;

    __shared__ float hs[8][INDIM];
    const int tiles = (NN + 7) / 8;
    for (int tile = blockIdx.x; tile < tiles; tile += gridDim.x) {
        const int base = tile * 8;
        __syncthreads();
#pragma unroll
        for (int j = 0; j < 3; ++j) {
            int flat = j * 256 + t;        // 0..767 covers 8*96
            int nd = flat / INDIM;
            int k = flat - nd * INDIM;
            int n = base + nd;
            float v = 0.f;
            if (n < NN)
                v = (k < INC) ? x[(size_t)n * INC + k]
                              : Wt[(size_t)ts[n] * TDIM + (k - INC)];
            hs[nd][k] = v;
        }
        __syncthreads();
#pragma unroll
        for (int nd = 0; nd < 8; ++nd) {
            int n = base + nd;
            if (n >= NN) break;
            const float4* hp = reinterpret_cast<const float4*>(&hs[nd][0]);
            float acc = bias;
#pragma unroll
            for (int k4 = 0; k4 < INDIM / 4; ++k4) {
                float4 hv = hp[k4];
                acc += wreg[4*k4+0]*hv.x + wreg[4*k4+1]*hv.y
                     + wreg[4*k4+2]*hv.z + wreg[4*k4+3]*hv.w;
            }
            outp[(size_t)n * D1 + col] = __float2half(acc);
        }
    }
}

// ================= bucketed CSR build =================

// ---- pass A: bin edges by dst-bucket; packed (src | dst<<16) appended at bucket tail
__global__ __launch_bounds__(256) void k_bin(
    const int* __restrict__ ei, int* __restrict__ bcnt, unsigned* __restrict__ stage)
{
    int e = blockIdx.x * 256 + threadIdx.x;
    if (e >= EP) return;
    int s, d;
    if (e < NE) { s = ei[e]; d = ei[NE + e]; }
    else        { s = e - NE; d = s; }
    int b = d >> 4;
    int pos = atomicAdd(&bcnt[b * PADC], 1);
    if (pos < CAP) stage[(size_t)b * CAP + pos] = (unsigned)s | ((unsigned)d << 16);
}

// ---- scan bucket counts -> bucket bases
__global__ __launch_bounds__(1024) void k_bscan(
    const int* __restrict__ bcnt, int* __restrict__ bbase, int* __restrict__ rowst)
{
    __shared__ int sums[1024];
    const int t = threadIdx.x;
    const int chunk = (NB + 1023) / 1024;   // 4
    int loc[4];
    int s = 0;
    for (int i = 0; i < chunk; ++i) {
        int idx = t * chunk + i;
        int v = (idx < NB) ? min(bcnt[idx * PADC], CAP) : 0;
        loc[i] = s;
        s += v;
    }
    sums[t] = s;
    __syncthreads();
    for (int off = 1; off < 1024; off <<= 1) {
        int add = (t >= off) ? sums[t - off] : 0;
        __syncthreads();
        sums[t] += add;
        __syncthreads();
    }
    int run = sums[t] - s;   // exclusive prefix over threads
    for (int i = 0; i < chunk; ++i) {
        int idx = t * chunk + i;
        if (idx < NB) bbase[idx] = run + loc[i];
    }
    if (t == 0) rowst[NN] = EP;
}

// ---- pass B: per bucket: LDS hist over 16 dsts -> rowst; scatter src (u16) into csr window
__global__ __launch_bounds__(256) void k_build(
    const int* __restrict__ bcnt, const int* __restrict__ bbase,
    const unsigned* __restrict__ stage,
    int* __restrict__ rowst, unsigned short* __restrict__ csr)
{
    const int b = blockIdx.x;
    const int t = threadIdx.x;
    const int cnt = min(bcnt[b * PADC], CAP);
    const int base = bbase[b];
    __shared__ int hist[16], curs[16];
    if (t < 16) hist[t] = 0;
    __syncthreads();
    unsigned pk[3];                   // CAP/256 = 3 max per thread
    int np = 0;
    for (int i = t; i < cnt; i += 256) {
        unsigned v = stage[(size_t)b * CAP + i];
        pk[np++] = v;
        atomicAdd(&hist[(v >> 16) & 15], 1);
    }
    __syncthreads();
    if (t < 16) {
        int excl = 0;
        for (int j = 0; j < t; ++j) excl += hist[j];
        rowst[b * 16 + t] = base + excl;
        curs[t] = excl;
    }
    __syncthreads();
    for (int i = 0; i < np; ++i) {
        unsigned v = pk[i];
        int pos = atomicAdd(&curs[(v >> 16) & 15], 1);
        csr[base + pos] = (unsigned short)(v & 0xFFFFu);
    }
}

// ================= aggregation / dense =================

// ---- layer-0 fused: 2 edges/wave (lane slot = lane>>5), 4 fp16 channels/lane,
//      packed-fp16 logit (v_pk_* via ext-vector ops) + fdot2, 3-shuffle head reduce
__global__ __launch_bounds__(256) void k_agg0(
    const int* __restrict__ rowst, const unsigned short* __restrict__ csr,
    const __half* __restrict__ xl0, const __half* __restrict__ xr0,
    const float* __restrict__ att0, const float* __restrict__ bias0,
    float* __restrict__ h1)
{
    const int d = (blockIdx.x * 256 + threadIdx.x) >> 6;
    const int lane = threadIdx.x & 63;
    if (d >= NN) return;
    const int slot  = lane >> 5;          // which edge of the pair
    const int lane5 = lane & 31;
    const int c0 = lane5 * 4;             // 4 channels c0..c0+3 (head = lane5>>3)

    H2U xr01u, xr23u;
    { uint2 w = *reinterpret_cast<const uint2*>(xr0 + (size_t)d * D1 + c0);
      xr01u.u = w.x; xr23u.u = w.y; }
    float4 atf = *reinterpret_cast<const float4*>(att0 + c0);
    H2U at01u, at23u;
    at01u.h = __floats2half2_rn(atf.x, atf.y);
    at23u.h = __floats2half2_rn(atf.z, atf.w);
    const _Float16 kneg = (_Float16)NEG;
    const h2v k2 = { kneg, kneg };

    const int rs = rowst[d];
    const int cnt = rowst[d + 1] - rs;
    float acc0 = 0.f, acc1 = 0.f, acc2 = 0.f, acc3 = 0.f, wsum = 0.f;

    int i = 0;
    for (; i + 8 <= cnt; i += 8) {
        int sv[4];
#pragma unroll
        for (int j = 0; j < 4; ++j) sv[j] = csr[rs + i + 2 * j + slot];
        uint2 xw[4];
#pragma unroll
        for (int j = 0; j < 4; ++j)
            xw[j] = *reinterpret_cast<const uint2*>(xl0 + (size_t)sv[j] * D1 + c0);
#pragma unroll
        for (int j = 0; j < 4; ++j) {
            H2U x01u, x23u; x01u.u = xw[j].x; x23u.u = xw[j].y;
            h2v s01 = x01u.v + xr01u.v;
            h2v s23 = x23u.v + xr23u.v;
            h2v l01 = __builtin_elementwise_max(s01, s01 * k2);
            h2v l23 = __builtin_elementwise_max(s23, s23 * k2);
            float p = __builtin_amdgcn_fdot2(l01, at01u.v,
                      __builtin_amdgcn_fdot2(l23, at23u.v, 0.f, false), false);
            p += __shfl_xor(p, 1);
            p += __shfl_xor(p, 2);
            p += __shfl_xor(p, 4);        // 8-lane (one head, one slot) reduce
            float wgt = __expf(p);
            float2 f01 = __half22float2(x01u.h);
            float2 f23 = __half22float2(x23u.h);
            wsum += wgt;
            acc0 += wgt * f01.x; acc1 += wgt * f01.y;
            acc2 += wgt * f23.x; acc3 += wgt * f23.y;
        }
    }
    for (; i < cnt; i += 2) {
        int e = i + slot;
        bool valid = (e < cnt);
        int s = csr[rs + (valid ? e : 0)];
        uint2 w = *reinterpret_cast<const uint2*>(xl0 + (size_t)s * D1 + c0);
        H2U x01u, x23u; x01u.u = w.x; x23u.u = w.y;
        h2v s01 = x01u.v + xr01u.v;
        h2v s23 = x23u.v + xr23u.v;
        h2v l01 = __builtin_elementwise_max(s01, s01 * k2);
        h2v l23 = __builtin_elementwise_max(s23, s23 * k2);
        float p = __builtin_amdgcn_fdot2(l01, at01u.v,
                  __builtin_amdgcn_fdot2(l23, at23u.v, 0.f, false), false);
        p += __shfl_xor(p, 1);
        p += __shfl_xor(p, 2);
        p += __shfl_xor(p, 4);
        float wgt = valid ? __expf(p) : 0.f;
        float2 f01 = __half22float2(x01u.h);
        float2 f23 = __half22float2(x23u.h);
        wsum += wgt;
        acc0 += wgt * f01.x; acc1 += wgt * f01.y;
        acc2 += wgt * f23.x; acc3 += wgt * f23.y;
    }

    // combine the two edge-slots
    acc0 += __shfl_xor(acc0, 32);
    acc1 += __shfl_xor(acc1, 32);
    acc2 += __shfl_xor(acc2, 32);
    acc3 += __shfl_xor(acc3, 32);
    wsum += __shfl_xor(wsum, 32);

    if (slot == 0) {
        float r = 1.f / (wsum + 1e-16f);
        float4 b = *reinterpret_cast<const float4*>(bias0 + c0);
        float4 o;
        o.x = fmaxf(acc0 * r + b.x, 0.f);
        o.y = fmaxf(acc1 * r + b.y, 0.f);
        o.z = fmaxf(acc2 * r + b.z, 0.f);
        o.w = fmaxf(acc3 * r + b.w, 0.f);
        *reinterpret_cast<float4*>(h1 + (size_t)d * D1 + c0) = o;
    }
}

// ---- GEMM1: xl1 = h1@Wl1+bl1 ; xr1 = h1@Wr1+br1   (thread per node)
__global__ __launch_bounds__(256) void k_gemm1(
    const float* __restrict__ h1,
    const float* __restrict__ Wl, const float* __restrict__ bl,
    const float* __restrict__ Wr, const float* __restrict__ br,
    float* __restrict__ xl1, float* __restrict__ xr1)
{
    __shared__ float wls[D1 * 2], wrs[D1 * 2];
    const int t = threadIdx.x;
    wls[t] = Wl[t]; wrs[t] = Wr[t];
    __syncthreads();
    int n = blockIdx.x * 256 + t;
    if (n >= NN) return;
    float al0 = bl[0], al1 = bl[1], ar0 = br[0], ar1 = br[1];
    const float4* hp = reinterpret_cast<const float4*>(h1 + (size_t)n * D1);
    const float2* wl2 = reinterpret_cast<const float2*>(wls);
    const float2* wr2 = reinterpret_cast<const float2*>(wrs);
#pragma unroll
    for (int k4 = 0; k4 < D1 / 4; ++k4) {
        float4 hv = hp[k4];
        int k = k4 * 4;
        float2 a, b;
        a = wl2[k+0]; b = wr2[k+0]; al0 += hv.x*a.x; al1 += hv.x*a.y; ar0 += hv.x*b.x; ar1 += hv.x*b.y;
        a = wl2[k+1]; b = wr2[k+1]; al0 += hv.y*a.x; al1 += hv.y*a.y; ar0 += hv.y*b.x; ar1 += hv.y*b.y;
        a = wl2[k+2]; b = wr2[k+2]; al0 += hv.z*a.x; al1 += hv.z*a.y; ar0 += hv.z*b.x; ar1 += hv.z*b.y;
        a = wl2[k+3]; b = wr2[k+3]; al0 += hv.w*a.x; al1 += hv.w*a.y; ar0 += hv.w*b.x; ar1 += hv.w*b.y;
    }
    *reinterpret_cast<float2*>(xl1 + (size_t)n * 2) = make_float2(al0, al1);
    *reinterpret_cast<float2*>(xr1 + (size_t)n * 2) = make_float2(ar0, ar1);
}

// ---- layer-1 fused: thread per dst; 4-deep pipelined gather, normalize at end
__global__ __launch_bounds__(256) void k_layer1(
    const int* __restrict__ rowst, const unsigned short* __restrict__ csr,
    const float* __restrict__ xl1, const float* __restrict__ xr1,
    const float* __restrict__ att1, const float* __restrict__ bias1,
    float* __restrict__ out)
{
    int d = blockIdx.x * 256 + threadIdx.x;
    if (d >= NN) return;
    float2 xr = *reinterpret_cast<const float2*>(xr1 + (size_t)d * 2);
    float A0 = att1[0], A1 = att1[1];
    int rs = rowst[d], re = rowst[d + 1];
    float sum = 0.f, a0 = 0.f, a1 = 0.f;
    int i = rs;
    for (; i + 4 <= re; i += 4) {
        int s0 = csr[i], s1 = csr[i+1], s2 = csr[i+2], s3 = csr[i+3];
        float2 x0 = *reinterpret_cast<const float2*>(xl1 + (size_t)s0 * 2);
        float2 x1 = *reinterpret_cast<const float2*>(xl1 + (size_t)s1 * 2);
        float2 x2 = *reinterpret_cast<const float2*>(xl1 + (size_t)s2 * 2);
        float2 x3 = *reinterpret_cast<const float2*>(xl1 + (size_t)s3 * 2);
        float w0 = __expf(lrelu(x0.x + xr.x) * A0 + lrelu(x0.y + xr.y) * A1);
        float w1 = __expf(lrelu(x1.x + xr.x) * A0 + lrelu(x1.y + xr.y) * A1);
        float w2 = __expf(lrelu(x2.x + xr.x) * A0 + lrelu(x2.y + xr.y) * A1);
        float w3 = __expf(lrelu(x3.x + xr.x) * A0 + lrelu(x3.y + xr.y) * A1);
        sum += w0 + w1 + w2 + w3;
        a0 += w0 * x0.x + w1 * x1.x + w2 * x2.x + w3 * x3.x;
        a1 += w0 * x0.y + w1 * x1.y + w2 * x2.y + w3 * x3.y;
    }
    for (; i < re; ++i) {
        int s = csr[i];
        float2 xs = *reinterpret_cast<const float2*>(xl1 + (size_t)s * 2);
        float wgt = __expf(lrelu(xs.x + xr.x) * A0 + lrelu(xs.y + xr.y) * A1);
        sum += wgt;
        a0 += wgt * xs.x;
        a1 += wgt * xs.y;
    }
    float r = 1.f / (sum + 1e-16f);
    out[(size_t)d * 2]     = a0 * r + bias1[0];
    out[(size_t)d * 2 + 1] = a1 * r + bias1[1];
}

extern "C" void kernel_launch(void* const* d_in, const int* in_sizes, int n_in,
                              void* d_out, int out_size, void* d_ws, size_t ws_size,
                              hipStream_t stream)
{
    const float* x     = (const float*)d_in[0];
    const int*   ei    = (const int*)d_in[1];
    const int*   ts    = (const int*)d_in[2];
    const float* Wt    = (const float*)d_in[3];
    const float* Wl0   = (const float*)d_in[4];
    const float* bl0   = (const float*)d_in[5];
    const float* Wr0   = (const float*)d_in[6];
    const float* br0   = (const float*)d_in[7];
    const float* att0  = (const float*)d_in[8];
    const float* bias0 = (const float*)d_in[9];
    const float* Wl1   = (const float*)d_in[10];
    const float* bl1   = (const float*)d_in[11];
    const float* Wr1   = (const float*)d_in[12];
    const float* br1   = (const float*)d_in[13];
    const float* att1  = (const float*)d_in[14];
    const float* bias1 = (const float*)d_in[15];
    float* out = (float*)d_out;

    char* wsp = (char*)d_ws;
    size_t off = 0;
    auto alloc = [&](size_t bytes) -> void* {
        void* p = wsp + off;
        off += (bytes + 255) & ~(size_t)255;
        return p;
    };
    __half* xl0  = (__half*)alloc((size_t)NN * D1 * 2);
    __half* xr0  = (__half*)alloc((size_t)NN * D1 * 2);
    float* h1    = (float*)alloc((size_t)NN * D1 * 4);
    float* xl1   = (float*)alloc((size_t)NN * 2 * 4);
    float* xr1   = (float*)alloc((size_t)NN * 2 * 4);
    int* rowst   = (int*)alloc((size_t)(NN + 1) * 4);
    unsigned short* csr = (unsigned short*)alloc((size_t)EP * 2);
    int* bcnt        = (int*)alloc((size_t)NB * PADC * 4);
    int* bbase       = (int*)alloc((size_t)NB * 4);
    unsigned* stage  = (unsigned*)alloc((size_t)NB * CAP * 4);

    k_gemm0<<<512, 256, 0, stream>>>(x, ts, Wt, Wl0, bl0, Wr0, br0, xl0, xr0);

    (void)hipMemsetAsync(bcnt, 0, (size_t)NB * PADC * 4, stream);
    k_bin<<<(EP + 255) / 256, 256, 0, stream>>>(ei, bcnt, stage);
    k_bscan<<<1, 1024, 0, stream>>>(bcnt, bbase, rowst);
    k_build<<<NB, 256, 0, stream>>>(bcnt, bbase, stage, rowst, csr);

    k_agg0<<<(NN + 3) / 4, 256, 0, stream>>>(rowst, csr, xl0, xr0, att0, bias0, h1);
    k_gemm1<<<(NN + 255) / 256, 256, 0, stream>>>(h1, Wl1, bl1, Wr1, br1, xl1, xr1);
    k_layer1<<<(NN + 255) / 256, 256, 0, stream>>>(rowst, csr, xl1, xr1, att1, bias1, out);
}

// Round 11
// 205.266 us; speedup vs baseline: 3.5496x; 1.2502x over previous
//
#include <hip/hip_runtime.h>
#include <hip/hip_fp16.h>

#define NN 50000
#define NE 1600000
#define EP (NE + NN)          // edges + self loops = 1,650,000
#define INC 64
#define TDIM 32
#define INDIM 96
#define D1 128
#define NEG 0.2f

// two-level partition: 98 coarse buckets of 512 dsts
#define CBSH 9
#define NCB 98                // ceil(NN / 512)
#define GCAP 18432            // per-coarse-bucket capacity (mean 16900, +12 sigma)
#define TILE 8192

typedef _Float16 h2v __attribute__((ext_vector_type(2)));
union H2U { unsigned u; __half2 h; h2v v; };

__device__ __forceinline__ float lrelu(float v) { return v > 0.f ? v : NEG * v; }

// ---- GEMM0: h=[x | W_time[ts]];  xl0 = h@Wl0+bl0 ; xr0 = h@Wr0+br0  (fp16 out)
__global__ __launch_bounds__(256) void k_gemm0(
    const float* __restrict__ x, const int* __restrict__ ts,
    const float* __restrict__ Wt,
    const float* __restrict__ Wl, const float* __restrict__ bl,
    const float* __restrict__ Wr, const float* __restrict__ br,
    __half* __restrict__ xl0, __half* __restrict__ xr0)
{
    const int t = threadIdx.x;
    const int col = t & 127;
    const bool isR = (t >= 128);
    const float* __restrict__ W = isR ? Wr : Wl;
    float wreg[INDIM];
#pragma unroll
    for (int k = 0; k < INDIM; ++k) wreg[k] = W[k * D1 + col];
    const float bias = isR ? br[col] : bl[col];
    __half* __restrict__ outp = isR ? xr0 : xl0;

    __shared__ float hs[8][INDIM];
    const int tiles = (NN + 7) / 8;
    for (int tile = blockIdx.x; tile < tiles; tile += gridDim.x) {
        const int base = tile * 8;
        __syncthreads();
#pragma unroll
        for (int j = 0; j < 3; ++j) {
            int flat = j * 256 + t;        // 0..767 covers 8*96
            int nd = flat / INDIM;
            int k = flat - nd * INDIM;
            int n = base + nd;
            float v = 0.f;
            if (n < NN)
                v = (k < INC) ? x[(size_t)n * INC + k]
                              : Wt[(size_t)ts[n] * TDIM + (k - INC)];
            hs[nd][k] = v;
        }
        __syncthreads();
#pragma unroll
        for (int nd = 0; nd < 8; ++nd) {
            int n = base + nd;
            if (n >= NN) break;
            const float4* hp = reinterpret_cast<const float4*>(&hs[nd][0]);
            float acc = bias;
#pragma unroll
            for (int k4 = 0; k4 < INDIM / 4; ++k4) {
                float4 hv = hp[k4];
                acc += wreg[4*k4+0]*hv.x + wreg[4*k4+1]*hv.y
                     + wreg[4*k4+2]*hv.z + wreg[4*k4+3]*hv.w;
            }
            outp[(size_t)n * D1 + col] = __float2half(acc);
        }
    }
}

// ================= two-level CSR build =================

// ---- pass A: LDS-staged coarse partition; coalesced flush into per-bucket runs
__global__ __launch_bounds__(1024) void k_part(
    const int* __restrict__ ei, int* __restrict__ gcnt, unsigned* __restrict__ cstage)
{
    __shared__ int cnt[NCB], loff[NCB + 1], gbasel[NCB], lpos[NCB];
    __shared__ unsigned pay[TILE];
    const int t = threadIdx.x;
    const int ntiles = (EP + TILE - 1) / TILE;
    for (int tile = blockIdx.x; tile < ntiles; tile += gridDim.x) {
        const int tb = tile * TILE;
        const int tc = min(TILE, EP - tb);
        if (t < NCB) cnt[t] = 0;
        __syncthreads();
        unsigned pk0, pk1, pk2, pk3, pk4, pk5, pk6, pk7;
#define LOADK(K, PK)                                              \
        {   int i = t + (K) * 1024;                               \
            if (i < tc) {                                         \
                int e = tb + i; int s, d;                         \
                if (e < NE) { s = ei[e]; d = ei[NE + e]; }        \
                else        { s = e - NE; d = s; }                \
                PK = ((unsigned)d << 16) | (unsigned)s;           \
                atomicAdd(&cnt[d >> CBSH], 1);                    \
            } }
        LOADK(0, pk0) LOADK(1, pk1) LOADK(2, pk2) LOADK(3, pk3)
        LOADK(4, pk4) LOADK(5, pk5) LOADK(6, pk6) LOADK(7, pk7)
#undef LOADK
        __syncthreads();
        if (t == 0) {
            int run = 0;
            for (int b = 0; b < NCB; ++b) { loff[b] = run; run += cnt[b]; }
            loff[NCB] = run;
        }
        __syncthreads();
        if (t < NCB) {
            gbasel[t] = atomicAdd(&gcnt[t], cnt[t]);
            lpos[t] = loff[t];
        }
        __syncthreads();
#define PLACEK(K, PK)                                             \
        {   int i = t + (K) * 1024;                               \
            if (i < tc) {                                         \
                int cb = (int)(PK >> (16 + CBSH));                \
                int p = atomicAdd(&lpos[cb], 1);                  \
                pay[p] = PK;                                      \
            } }
        PLACEK(0, pk0) PLACEK(1, pk1) PLACEK(2, pk2) PLACEK(3, pk3)
        PLACEK(4, pk4) PLACEK(5, pk5) PLACEK(6, pk6) PLACEK(7, pk7)
#undef PLACEK
        __syncthreads();
        for (int j = t; j < tc; j += 1024) {
            int lo = 0, hi = NCB - 1;                 // last b with loff[b] <= j
            while (lo < hi) { int mid = (lo + hi + 1) >> 1;
                              if (loff[mid] <= j) lo = mid; else hi = mid - 1; }
            int pos = gbasel[lo] + (j - loff[lo]);
            if (pos < GCAP) cstage[(size_t)lo * GCAP + pos] = pay[j];
        }
        __syncthreads();
    }
}

// ---- tiny scan over coarse buckets
__global__ void k_cscan(const int* __restrict__ gcnt, int* __restrict__ gbase,
                        int* __restrict__ rowst)
{
    if (threadIdx.x == 0) {
        int run = 0;
        for (int b = 0; b < NCB; ++b) { gbase[b] = run; run += min(gcnt[b], GCAP); }
        rowst[NN] = run;
    }
}

// ---- pass B: per coarse bucket: 512-dst LDS hist -> rowst; scatter u16 src into csr window
__global__ __launch_bounds__(1024) void k_build2(
    const int* __restrict__ gcnt, const int* __restrict__ gbase,
    const unsigned* __restrict__ cstage,
    int* __restrict__ rowst, unsigned short* __restrict__ csr)
{
    const int b = blockIdx.x;
    const int t = threadIdx.x;
    __shared__ int hist[512], sc[512], curs[512];
    const int cnt = min(gcnt[b], GCAP);
    const int base = gbase[b];
    const int d0 = b << CBSH;
    const int nd = min(512, NN - d0);
    if (t < 512) hist[t] = 0;
    __syncthreads();
    const unsigned* __restrict__ src = cstage + (size_t)b * GCAP;
    for (int i = t; i < cnt; i += 1024)
        atomicAdd(&hist[(src[i] >> 16) & 511], 1);
    __syncthreads();
    if (t < 512) sc[t] = hist[t];
    __syncthreads();
    for (int off = 1; off < 512; off <<= 1) {
        int v = 0;
        if (t < 512 && t >= off) v = sc[t - off];
        __syncthreads();
        if (t < 512) sc[t] += v;
        __syncthreads();
    }
    if (t < 512) {
        int excl = sc[t] - hist[t];
        curs[t] = excl;
        if (t < nd) rowst[d0 + t] = base + excl;
    }
    __syncthreads();
    for (int i = t; i < cnt; i += 1024) {
        unsigned v = src[i];
        int p = atomicAdd(&curs[(v >> 16) & 511], 1);
        csr[base + p] = (unsigned short)(v & 0xFFFFu);
    }
}

// ================= aggregation / dense =================

// ---- layer-0 fused: 2 edges/wave, 4 fp16 channels/lane, packed logit + fdot2
__global__ __launch_bounds__(256) void k_agg0(
    const int* __restrict__ rowst, const unsigned short* __restrict__ csr,
    const __half* __restrict__ xl0, const __half* __restrict__ xr0,
    const float* __restrict__ att0, const float* __restrict__ bias0,
    float* __restrict__ h1)
{
    const int d = (blockIdx.x * 256 + threadIdx.x) >> 6;
    const int lane = threadIdx.x & 63;
    if (d >= NN) return;
    const int slot  = lane >> 5;
    const int lane5 = lane & 31;
    const int c0 = lane5 * 4;

    H2U xr01u, xr23u;
    { uint2 w = *reinterpret_cast<const uint2*>(xr0 + (size_t)d * D1 + c0);
      xr01u.u = w.x; xr23u.u = w.y; }
    float4 atf = *reinterpret_cast<const float4*>(att0 + c0);
    H2U at01u, at23u;
    at01u.h = __floats2half2_rn(atf.x, atf.y);
    at23u.h = __floats2half2_rn(atf.z, atf.w);
    const _Float16 kneg = (_Float16)NEG;
    const h2v k2 = { kneg, kneg };

    const int rs = rowst[d];
    const int cnt = rowst[d + 1] - rs;
    float acc0 = 0.f, acc1 = 0.f, acc2 = 0.f, acc3 = 0.f, wsum = 0.f;

    int i = 0;
    for (; i + 8 <= cnt; i += 8) {
        int sv[4];
#pragma unroll
        for (int j = 0; j < 4; ++j) sv[j] = csr[rs + i + 2 * j + slot];
        uint2 xw[4];
#pragma unroll
        for (int j = 0; j < 4; ++j)
            xw[j] = *reinterpret_cast<const uint2*>(xl0 + (size_t)sv[j] * D1 + c0);
#pragma unroll
        for (int j = 0; j < 4; ++j) {
            H2U x01u, x23u; x01u.u = xw[j].x; x23u.u = xw[j].y;
            h2v s01 = x01u.v + xr01u.v;
            h2v s23 = x23u.v + xr23u.v;
            h2v l01 = __builtin_elementwise_max(s01, s01 * k2);
            h2v l23 = __builtin_elementwise_max(s23, s23 * k2);
            float p = __builtin_amdgcn_fdot2(l01, at01u.v,
                      __builtin_amdgcn_fdot2(l23, at23u.v, 0.f, false), false);
            p += __shfl_xor(p, 1);
            p += __shfl_xor(p, 2);
            p += __shfl_xor(p, 4);
            float wgt = __expf(p);
            float2 f01 = __half22float2(x01u.h);
            float2 f23 = __half22float2(x23u.h);
            wsum += wgt;
            acc0 += wgt * f01.x; acc1 += wgt * f01.y;
            acc2 += wgt * f23.x; acc3 += wgt * f23.y;
        }
    }
    for (; i < cnt; i += 2) {
        int e = i + slot;
        bool valid = (e < cnt);
        int s = csr[rs + (valid ? e : 0)];
        uint2 w = *reinterpret_cast<const uint2*>(xl0 + (size_t)s * D1 + c0);
        H2U x01u, x23u; x01u.u = w.x; x23u.u = w.y;
        h2v s01 = x01u.v + xr01u.v;
        h2v s23 = x23u.v + xr23u.v;
        h2v l01 = __builtin_elementwise_max(s01, s01 * k2);
        h2v l23 = __builtin_elementwise_max(s23, s23 * k2);
        float p = __builtin_amdgcn_fdot2(l01, at01u.v,
                  __builtin_amdgcn_fdot2(l23, at23u.v, 0.f, false), false);
        p += __shfl_xor(p, 1);
        p += __shfl_xor(p, 2);
        p += __shfl_xor(p, 4);
        float wgt = valid ? __expf(p) : 0.f;
        float2 f01 = __half22float2(x01u.h);
        float2 f23 = __half22float2(x23u.h);
        wsum += wgt;
        acc0 += wgt * f01.x; acc1 += wgt * f01.y;
        acc2 += wgt * f23.x; acc3 += wgt * f23.y;
    }

    acc0 += __shfl_xor(acc0, 32);
    acc1 += __shfl_xor(acc1, 32);
    acc2 += __shfl_xor(acc2, 32);
    acc3 += __shfl_xor(acc3, 32);
    wsum += __shfl_xor(wsum, 32);

    if (slot == 0) {
        float r = 1.f / (wsum + 1e-16f);
        float4 b = *reinterpret_cast<const float4*>(bias0 + c0);
        float4 o;
        o.x = fmaxf(acc0 * r + b.x, 0.f);
        o.y = fmaxf(acc1 * r + b.y, 0.f);
        o.z = fmaxf(acc2 * r + b.z, 0.f);
        o.w = fmaxf(acc3 * r + b.w, 0.f);
        *reinterpret_cast<float4*>(h1 + (size_t)d * D1 + c0) = o;
    }
}

// ---- GEMM1: xl1 = h1@Wl1+bl1 ; xr1 = h1@Wr1+br1   (thread per node)
__global__ __launch_bounds__(256) void k_gemm1(
    const float* __restrict__ h1,
    const float* __restrict__ Wl, const float* __restrict__ bl,
    const float* __restrict__ Wr, const float* __restrict__ br,
    float* __restrict__ xl1, float* __restrict__ xr1)
{
    __shared__ float wls[D1 * 2], wrs[D1 * 2];
    const int t = threadIdx.x;
    wls[t] = Wl[t]; wrs[t] = Wr[t];
    __syncthreads();
    int n = blockIdx.x * 256 + t;
    if (n >= NN) return;
    float al0 = bl[0], al1 = bl[1], ar0 = br[0], ar1 = br[1];
    const float4* hp = reinterpret_cast<const float4*>(h1 + (size_t)n * D1);
    const float2* wl2 = reinterpret_cast<const float2*>(wls);
    const float2* wr2 = reinterpret_cast<const float2*>(wrs);
#pragma unroll
    for (int k4 = 0; k4 < D1 / 4; ++k4) {
        float4 hv = hp[k4];
        int k = k4 * 4;
        float2 a, b;
        a = wl2[k+0]; b = wr2[k+0]; al0 += hv.x*a.x; al1 += hv.x*a.y; ar0 += hv.x*b.x; ar1 += hv.x*b.y;
        a = wl2[k+1]; b = wr2[k+1]; al0 += hv.y*a.x; al1 += hv.y*a.y; ar0 += hv.y*b.x; ar1 += hv.y*b.y;
        a = wl2[k+2]; b = wr2[k+2]; al0 += hv.z*a.x; al1 += hv.z*a.y; ar0 += hv.z*b.x; ar1 += hv.z*b.y;
        a = wl2[k+3]; b = wr2[k+3]; al0 += hv.w*a.x; al1 += hv.w*a.y; ar0 += hv.w*b.x; ar1 += hv.w*b.y;
    }
    *reinterpret_cast<float2*>(xl1 + (size_t)n * 2) = make_float2(al0, al1);
    *reinterpret_cast<float2*>(xr1 + (size_t)n * 2) = make_float2(ar0, ar1);
}

// ---- layer-1 fused: thread per dst; 4-deep pipelined gather, normalize at end
__global__ __launch_bounds__(256) void k_layer1(
    const int* __restrict__ rowst, const unsigned short* __restrict__ csr,
    const float* __restrict__ xl1, const float* __restrict__ xr1,
    const float* __restrict__ att1, const float* __restrict__ bias1,
    float* __restrict__ out)
{
    int d = blockIdx.x * 256 + threadIdx.x;
    if (d >= NN) return;
    float2 xr = *reinterpret_cast<const float2*>(xr1 + (size_t)d * 2);
    float A0 = att1[0], A1 = att1[1];
    int rs = rowst[d], re = rowst[d + 1];
    float sum = 0.f, a0 = 0.f, a1 = 0.f;
    int i = rs;
    for (; i + 4 <= re; i += 4) {
        int s0 = csr[i], s1 = csr[i+1], s2 = csr[i+2], s3 = csr[i+3];
        float2 x0 = *reinterpret_cast<const float2*>(xl1 + (size_t)s0 * 2);
        float2 x1 = *reinterpret_cast<const float2*>(xl1 + (size_t)s1 * 2);
        float2 x2 = *reinterpret_cast<const float2*>(xl1 + (size_t)s2 * 2);
        float2 x3 = *reinterpret_cast<const float2*>(xl1 + (size_t)s3 * 2);
        float w0 = __expf(lrelu(x0.x + xr.x) * A0 + lrelu(x0.y + xr.y) * A1);
        float w1 = __expf(lrelu(x1.x + xr.x) * A0 + lrelu(x1.y + xr.y) * A1);
        float w2 = __expf(lrelu(x2.x + xr.x) * A0 + lrelu(x2.y + xr.y) * A1);
        float w3 = __expf(lrelu(x3.x + xr.x) * A0 + lrelu(x3.y + xr.y) * A1);
        sum += w0 + w1 + w2 + w3;
        a0 += w0 * x0.x + w1 * x1.x + w2 * x2.x + w3 * x3.x;
        a1 += w0 * x0.y + w1 * x1.y + w2 * x2.y + w3 * x3.y;
    }
    for (; i < re; ++i) {
        int s = csr[i];
        float2 xs = *reinterpret_cast<const float2*>(xl1 + (size_t)s * 2);
        float wgt = __expf(lrelu(xs.x + xr.x) * A0 + lrelu(xs.y + xr.y) * A1);
        sum += wgt;
        a0 += wgt * xs.x;
        a1 += wgt * xs.y;
    }
    float r = 1.f / (sum + 1e-16f);
    out[(size_t)d * 2]     = a0 * r + bias1[0];
    out[(size_t)d * 2 + 1] = a1 * r + bias1[1];
}

extern "C" void kernel_launch(void* const* d_in, const int* in_sizes, int n_in,
                              void* d_out, int out_size, void* d_ws, size_t ws_size,
                              hipStream_t stream)
{
    const float* x     = (const float*)d_in[0];
    const int*   ei    = (const int*)d_in[1];
    const int*   ts    = (const int*)d_in[2];
    const float* Wt    = (const float*)d_in[3];
    const float* Wl0   = (const float*)d_in[4];
    const float* bl0   = (const float*)d_in[5];
    const float* Wr0   = (const float*)d_in[6];
    const float* br0   = (const float*)d_in[7];
    const float* att0  = (const float*)d_in[8];
    const float* bias0 = (const float*)d_in[9];
    const float* Wl1   = (const float*)d_in[10];
    const float* bl1   = (const float*)d_in[11];
    const float* Wr1   = (const float*)d_in[12];
    const float* br1   = (const float*)d_in[13];
    const float* att1  = (const float*)d_in[14];
    const float* bias1 = (const float*)d_in[15];
    float* out = (float*)d_out;

    char* wsp = (char*)d_ws;
    size_t off = 0;
    auto alloc = [&](size_t bytes) -> void* {
        void* p = wsp + off;
        off += (bytes + 255) & ~(size_t)255;
        return p;
    };
    __half* xl0  = (__half*)alloc((size_t)NN * D1 * 2);
    __half* xr0  = (__half*)alloc((size_t)NN * D1 * 2);
    float* h1    = (float*)alloc((size_t)NN * D1 * 4);
    float* xl1   = (float*)alloc((size_t)NN * 2 * 4);
    float* xr1   = (float*)alloc((size_t)NN * 2 * 4);
    int* rowst   = (int*)alloc((size_t)(NN + 1) * 4);
    unsigned short* csr = (unsigned short*)alloc((size_t)EP * 2);
    int* gcnt        = (int*)alloc((size_t)NCB * 4);
    int* gbase       = (int*)alloc((size_t)NCB * 4);
    unsigned* cstage = (unsigned*)alloc((size_t)NCB * GCAP * 4);

    k_gemm0<<<512, 256, 0, stream>>>(x, ts, Wt, Wl0, bl0, Wr0, br0, xl0, xr0);

    (void)hipMemsetAsync(gcnt, 0, (size_t)NCB * 4, stream);
    const int ntiles = (EP + TILE - 1) / TILE;
    k_part<<<ntiles, 1024, 0, stream>>>(ei, gcnt, cstage);
    k_cscan<<<1, 64, 0, stream>>>(gcnt, gbase, rowst);
    k_build2<<<NCB, 1024, 0, stream>>>(gcnt, gbase, cstage, rowst, csr);

    k_agg0<<<(NN + 3) / 4, 256, 0, stream>>>(rowst, csr, xl0, xr0, att0, bias0, h1);
    k_gemm1<<<(NN + 255) / 256, 256, 0, stream>>>(h1, Wl1, bl1, Wr1, br1, xl1, xr1);
    k_layer1<<<(NN + 255) / 256, 256, 0, stream>>>(rowst, csr, xl1, xr1, att1, bias1, out);
}

// Round 12
// 193.850 us; speedup vs baseline: 3.7587x; 1.0589x over previous
//
#include <hip/hip_runtime.h>
#include <hip/hip_fp16.h>

#define NN 50000
#define NE 1600000
#define EP (NE + NN)          // edges + self loops = 1,650,000
#define INC 64
#define TDIM 32
#define INDIM 96
#define D1 128
#define NEG 0.2f

// two-level partition: 98 coarse buckets of 512 dsts
#define CBSH 9
#define NCB 98                // ceil(NN / 512)
#define GCAP 18432            // per-coarse-bucket capacity (mean 16900, +12 sigma)
#define TILE 8192

typedef _Float16 h2v __attribute__((ext_vector_type(2)));
union H2U { unsigned u; __half2 h; h2v v; };

__device__ __forceinline__ float lrelu(float v) { return v > 0.f ? v : NEG * v; }

// ---- GEMM0: h=[x | W_time[ts]];  xl0 = h@Wl0+bl0 ; xr0 = h@Wr0+br0  (fp16 out)
//      2048 persistent blocks (7 blocks/CU at 68 VGPR); dual accumulators break FMA chain
__global__ __launch_bounds__(256) void k_gemm0(
    const float* __restrict__ x, const int* __restrict__ ts,
    const float* __restrict__ Wt,
    const float* __restrict__ Wl, const float* __restrict__ bl,
    const float* __restrict__ Wr, const float* __restrict__ br,
    __half* __restrict__ xl0, __half* __restrict__ xr0)
{
    const int t = threadIdx.x;
    const int col = t & 127;
    const bool isR = (t >= 128);
    const float* __restrict__ W = isR ? Wr : Wl;
    float wreg[INDIM];
#pragma unroll
    for (int k = 0; k < INDIM; ++k) wreg[k] = W[k * D1 + col];
    const float bias = isR ? br[col] : bl[col];
    __half* __restrict__ outp = isR ? xr0 : xl0;

    __shared__ float hs[8][INDIM];
    const int tiles = (NN + 7) / 8;
    for (int tile = blockIdx.x; tile < tiles; tile += gridDim.x) {
        const int base = tile * 8;
        __syncthreads();
#pragma unroll
        for (int j = 0; j < 3; ++j) {
            int flat = j * 256 + t;        // 0..767 covers 8*96
            int nd = flat / INDIM;
            int k = flat - nd * INDIM;
            int n = base + nd;
            float v = 0.f;
            if (n < NN)
                v = (k < INC) ? x[(size_t)n * INC + k]
                              : Wt[(size_t)ts[n] * TDIM + (k - INC)];
            hs[nd][k] = v;
        }
        __syncthreads();
#pragma unroll
        for (int nd = 0; nd < 8; ++nd) {
            int n = base + nd;
            if (n >= NN) break;
            const float4* hp = reinterpret_cast<const float4*>(&hs[nd][0]);
            float accA = bias, accB = 0.f;
#pragma unroll
            for (int k4 = 0; k4 < INDIM / 4; k4 += 2) {
                float4 h0 = hp[k4];
                float4 h1v_ = hp[k4 + 1];
                accA += wreg[4*k4+0]*h0.x + wreg[4*k4+1]*h0.y
                      + wreg[4*k4+2]*h0.z + wreg[4*k4+3]*h0.w;
                accB += wreg[4*k4+4]*h1v_.x + wreg[4*k4+5]*h1v_.y
                      + wreg[4*k4+6]*h1v_.z + wreg[4*k4+7]*h1v_.w;
            }
            outp[(size_t)n * D1 + col] = __float2half(accA + accB);
        }
    }
}

// ================= two-level CSR build =================

// ---- pass A: LDS-staged coarse partition; coalesced flush into per-bucket runs
__global__ __launch_bounds__(1024) void k_part(
    const int* __restrict__ ei, int* __restrict__ gcnt, unsigned* __restrict__ cstage)
{
    __shared__ int cnt[NCB], loff[NCB + 1], gbasel[NCB], lpos[NCB];
    __shared__ unsigned pay[TILE];
    const int t = threadIdx.x;
    const int ntiles = (EP + TILE - 1) / TILE;
    for (int tile = blockIdx.x; tile < ntiles; tile += gridDim.x) {
        const int tb = tile * TILE;
        const int tc = min(TILE, EP - tb);
        if (t < NCB) cnt[t] = 0;
        __syncthreads();
        unsigned pk0, pk1, pk2, pk3, pk4, pk5, pk6, pk7;
#define LOADK(K, PK)                                              \
        {   int i = t + (K) * 1024;                               \
            if (i < tc) {                                         \
                int e = tb + i; int s, d;                         \
                if (e < NE) { s = ei[e]; d = ei[NE + e]; }        \
                else        { s = e - NE; d = s; }                \
                PK = ((unsigned)d << 16) | (unsigned)s;           \
                atomicAdd(&cnt[d >> CBSH], 1);                    \
            } }
        LOADK(0, pk0) LOADK(1, pk1) LOADK(2, pk2) LOADK(3, pk3)
        LOADK(4, pk4) LOADK(5, pk5) LOADK(6, pk6) LOADK(7, pk7)
#undef LOADK
        __syncthreads();
        if (t == 0) {
            int run = 0;
            for (int b = 0; b < NCB; ++b) { loff[b] = run; run += cnt[b]; }
            loff[NCB] = run;
        }
        __syncthreads();
        if (t < NCB) {
            gbasel[t] = atomicAdd(&gcnt[t], cnt[t]);
            lpos[t] = loff[t];
        }
        __syncthreads();
#define PLACEK(K, PK)                                             \
        {   int i = t + (K) * 1024;                               \
            if (i < tc) {                                         \
                int cb = (int)(PK >> (16 + CBSH));                \
                int p = atomicAdd(&lpos[cb], 1);                  \
                pay[p] = PK;                                      \
            } }
        PLACEK(0, pk0) PLACEK(1, pk1) PLACEK(2, pk2) PLACEK(3, pk3)
        PLACEK(4, pk4) PLACEK(5, pk5) PLACEK(6, pk6) PLACEK(7, pk7)
#undef PLACEK
        __syncthreads();
        for (int j = t; j < tc; j += 1024) {
            int lo = 0, hi = NCB - 1;                 // last b with loff[b] <= j
            while (lo < hi) { int mid = (lo + hi + 1) >> 1;
                              if (loff[mid] <= j) lo = mid; else hi = mid - 1; }
            int pos = gbasel[lo] + (j - loff[lo]);
            if (pos < GCAP) cstage[(size_t)lo * GCAP + pos] = pay[j];
        }
        __syncthreads();
    }
}

// ---- tiny scan over coarse buckets
__global__ void k_cscan(const int* __restrict__ gcnt, int* __restrict__ gbase,
                        int* __restrict__ rowst)
{
    if (threadIdx.x == 0) {
        int run = 0;
        for (int b = 0; b < NCB; ++b) { gbase[b] = run; run += min(gcnt[b], GCAP); }
        rowst[NN] = run;
    }
}

// ---- pass B: per coarse bucket: 512-dst LDS hist -> rowst; scatter u16 src into csr window
__global__ __launch_bounds__(1024) void k_build2(
    const int* __restrict__ gcnt, const int* __restrict__ gbase,
    const unsigned* __restrict__ cstage,
    int* __restrict__ rowst, unsigned short* __restrict__ csr)
{
    const int b = blockIdx.x;
    const int t = threadIdx.x;
    __shared__ int hist[512], sc[512], curs[512];
    const int cnt = min(gcnt[b], GCAP);
    const int base = gbase[b];
    const int d0 = b << CBSH;
    const int nd = min(512, NN - d0);
    if (t < 512) hist[t] = 0;
    __syncthreads();
    const unsigned* __restrict__ src = cstage + (size_t)b * GCAP;
    for (int i = t; i < cnt; i += 1024)
        atomicAdd(&hist[(src[i] >> 16) & 511], 1);
    __syncthreads();
    if (t < 512) sc[t] = hist[t];
    __syncthreads();
    for (int off = 1; off < 512; off <<= 1) {
        int v = 0;
        if (t < 512 && t >= off) v = sc[t - off];
        __syncthreads();
        if (t < 512) sc[t] += v;
        __syncthreads();
    }
    if (t < 512) {
        int excl = sc[t] - hist[t];
        curs[t] = excl;
        if (t < nd) rowst[d0 + t] = base + excl;
    }
    __syncthreads();
    for (int i = t; i < cnt; i += 1024) {
        unsigned v = src[i];
        int p = atomicAdd(&curs[(v >> 16) & 511], 1);
        csr[base + p] = (unsigned short)(v & 0xFFFFu);
    }
}

// ================= aggregation / dense =================

// ---- layer-0 fused: 2 edges/wave, 4 fp16 channels/lane, packed logit + fdot2
__global__ __launch_bounds__(256) void k_agg0(
    const int* __restrict__ rowst, const unsigned short* __restrict__ csr,
    const __half* __restrict__ xl0, const __half* __restrict__ xr0,
    const float* __restrict__ att0, const float* __restrict__ bias0,
    float* __restrict__ h1)
{
    const int d = (blockIdx.x * 256 + threadIdx.x) >> 6;
    const int lane = threadIdx.x & 63;
    if (d >= NN) return;
    const int slot  = lane >> 5;
    const int lane5 = lane & 31;
    const int c0 = lane5 * 4;

    H2U xr01u, xr23u;
    { uint2 w = *reinterpret_cast<const uint2*>(xr0 + (size_t)d * D1 + c0);
      xr01u.u = w.x; xr23u.u = w.y; }
    float4 atf = *reinterpret_cast<const float4*>(att0 + c0);
    H2U at01u, at23u;
    at01u.h = __floats2half2_rn(atf.x, atf.y);
    at23u.h = __floats2half2_rn(atf.z, atf.w);
    const _Float16 kneg = (_Float16)NEG;
    const h2v k2 = { kneg, kneg };

    const int rs = rowst[d];
    const int cnt = rowst[d + 1] - rs;
    float acc0 = 0.f, acc1 = 0.f, acc2 = 0.f, acc3 = 0.f, wsum = 0.f;

    int i = 0;
    for (; i + 8 <= cnt; i += 8) {
        int sv[4];
#pragma unroll
        for (int j = 0; j < 4; ++j) sv[j] = csr[rs + i + 2 * j + slot];
        uint2 xw[4];
#pragma unroll
        for (int j = 0; j < 4; ++j)
            xw[j] = *reinterpret_cast<const uint2*>(xl0 + (size_t)sv[j] * D1 + c0);
#pragma unroll
        for (int j = 0; j < 4; ++j) {
            H2U x01u, x23u; x01u.u = xw[j].x; x23u.u = xw[j].y;
            h2v s01 = x01u.v + xr01u.v;
            h2v s23 = x23u.v + xr23u.v;
            h2v l01 = __builtin_elementwise_max(s01, s01 * k2);
            h2v l23 = __builtin_elementwise_max(s23, s23 * k2);
            float p = __builtin_amdgcn_fdot2(l01, at01u.v,
                      __builtin_amdgcn_fdot2(l23, at23u.v, 0.f, false), false);
            p += __shfl_xor(p, 1);
            p += __shfl_xor(p, 2);
            p += __shfl_xor(p, 4);
            float wgt = __expf(p);
            float2 f01 = __half22float2(x01u.h);
            float2 f23 = __half22float2(x23u.h);
            wsum += wgt;
            acc0 += wgt * f01.x; acc1 += wgt * f01.y;
            acc2 += wgt * f23.x; acc3 += wgt * f23.y;
        }
    }
    for (; i < cnt; i += 2) {
        int e = i + slot;
        bool valid = (e < cnt);
        int s = csr[rs + (valid ? e : 0)];
        uint2 w = *reinterpret_cast<const uint2*>(xl0 + (size_t)s * D1 + c0);
        H2U x01u, x23u; x01u.u = w.x; x23u.u = w.y;
        h2v s01 = x01u.v + xr01u.v;
        h2v s23 = x23u.v + xr23u.v;
        h2v l01 = __builtin_elementwise_max(s01, s01 * k2);
        h2v l23 = __builtin_elementwise_max(s23, s23 * k2);
        float p = __builtin_amdgcn_fdot2(l01, at01u.v,
                  __builtin_amdgcn_fdot2(l23, at23u.v, 0.f, false), false);
        p += __shfl_xor(p, 1);
        p += __shfl_xor(p, 2);
        p += __shfl_xor(p, 4);
        float wgt = valid ? __expf(p) : 0.f;
        float2 f01 = __half22float2(x01u.h);
        float2 f23 = __half22float2(x23u.h);
        wsum += wgt;
        acc0 += wgt * f01.x; acc1 += wgt * f01.y;
        acc2 += wgt * f23.x; acc3 += wgt * f23.y;
    }

    acc0 += __shfl_xor(acc0, 32);
    acc1 += __shfl_xor(acc1, 32);
    acc2 += __shfl_xor(acc2, 32);
    acc3 += __shfl_xor(acc3, 32);
    wsum += __shfl_xor(wsum, 32);

    if (slot == 0) {
        float r = 1.f / (wsum + 1e-16f);
        float4 b = *reinterpret_cast<const float4*>(bias0 + c0);
        float4 o;
        o.x = fmaxf(acc0 * r + b.x, 0.f);
        o.y = fmaxf(acc1 * r + b.y, 0.f);
        o.z = fmaxf(acc2 * r + b.z, 0.f);
        o.w = fmaxf(acc3 * r + b.w, 0.f);
        *reinterpret_cast<float4*>(h1 + (size_t)d * D1 + c0) = o;
    }
}

// ---- GEMM1: xl1 = h1@Wl1+bl1 ; xr1 = h1@Wr1+br1   (thread per node)
__global__ __launch_bounds__(256) void k_gemm1(
    const float* __restrict__ h1,
    const float* __restrict__ Wl, const float* __restrict__ bl,
    const float* __restrict__ Wr, const float* __restrict__ br,
    float* __restrict__ xl1, float* __restrict__ xr1)
{
    __shared__ float wls[D1 * 2], wrs[D1 * 2];
    const int t = threadIdx.x;
    wls[t] = Wl[t]; wrs[t] = Wr[t];
    __syncthreads();
    int n = blockIdx.x * 256 + t;
    if (n >= NN) return;
    float al0 = bl[0], al1 = bl[1], ar0 = br[0], ar1 = br[1];
    const float4* hp = reinterpret_cast<const float4*>(h1 + (size_t)n * D1);
    const float2* wl2 = reinterpret_cast<const float2*>(wls);
    const float2* wr2 = reinterpret_cast<const float2*>(wrs);
#pragma unroll
    for (int k4 = 0; k4 < D1 / 4; ++k4) {
        float4 hv = hp[k4];
        int k = k4 * 4;
        float2 a, b;
        a = wl2[k+0]; b = wr2[k+0]; al0 += hv.x*a.x; al1 += hv.x*a.y; ar0 += hv.x*b.x; ar1 += hv.x*b.y;
        a = wl2[k+1]; b = wr2[k+1]; al0 += hv.y*a.x; al1 += hv.y*a.y; ar0 += hv.y*b.x; ar1 += hv.y*b.y;
        a = wl2[k+2]; b = wr2[k+2]; al0 += hv.z*a.x; al1 += hv.z*a.y; ar0 += hv.z*b.x; ar1 += hv.z*b.y;
        a = wl2[k+3]; b = wr2[k+3]; al0 += hv.w*a.x; al1 += hv.w*a.y; ar0 += hv.w*b.x; ar1 += hv.w*b.y;
    }
    *reinterpret_cast<float2*>(xl1 + (size_t)n * 2) = make_float2(al0, al1);
    *reinterpret_cast<float2*>(xr1 + (size_t)n * 2) = make_float2(ar0, ar1);
}

// ---- layer-1 fused: thread per dst; 4-deep pipelined gather, normalize at end
__global__ __launch_bounds__(256) void k_layer1(
    const int* __restrict__ rowst, const unsigned short* __restrict__ csr,
    const float* __restrict__ xl1, const float* __restrict__ xr1,
    const float* __restrict__ att1, const float* __restrict__ bias1,
    float* __restrict__ out)
{
    int d = blockIdx.x * 256 + threadIdx.x;
    if (d >= NN) return;
    float2 xr = *reinterpret_cast<const float2*>(xr1 + (size_t)d * 2);
    float A0 = att1[0], A1 = att1[1];
    int rs = rowst[d], re = rowst[d + 1];
    float sum = 0.f, a0 = 0.f, a1 = 0.f;
    int i = rs;
    for (; i + 4 <= re; i += 4) {
        int s0 = csr[i], s1 = csr[i+1], s2 = csr[i+2], s3 = csr[i+3];
        float2 x0 = *reinterpret_cast<const float2*>(xl1 + (size_t)s0 * 2);
        float2 x1 = *reinterpret_cast<const float2*>(xl1 + (size_t)s1 * 2);
        float2 x2 = *reinterpret_cast<const float2*>(xl1 + (size_t)s2 * 2);
        float2 x3 = *reinterpret_cast<const float2*>(xl1 + (size_t)s3 * 2);
        float w0 = __expf(lrelu(x0.x + xr.x) * A0 + lrelu(x0.y + xr.y) * A1);
        float w1 = __expf(lrelu(x1.x + xr.x) * A0 + lrelu(x1.y + xr.y) * A1);
        float w2 = __expf(lrelu(x2.x + xr.x) * A0 + lrelu(x2.y + xr.y) * A1);
        float w3 = __expf(lrelu(x3.x + xr.x) * A0 + lrelu(x3.y + xr.y) * A1);
        sum += w0 + w1 + w2 + w3;
        a0 += w0 * x0.x + w1 * x1.x + w2 * x2.x + w3 * x3.x;
        a1 += w0 * x0.y + w1 * x1.y + w2 * x2.y + w3 * x3.y;
    }
    for (; i < re; ++i) {
        int s = csr[i];
        float2 xs = *reinterpret_cast<const float2*>(xl1 + (size_t)s * 2);
        float wgt = __expf(lrelu(xs.x + xr.x) * A0 + lrelu(xs.y + xr.y) * A1);
        sum += wgt;
        a0 += wgt * xs.x;
        a1 += wgt * xs.y;
    }
    float r = 1.f / (sum + 1e-16f);
    out[(size_t)d * 2]     = a0 * r + bias1[0];
    out[(size_t)d * 2 + 1] = a1 * r + bias1[1];
}

extern "C" void kernel_launch(void* const* d_in, const int* in_sizes, int n_in,
                              void* d_out, int out_size, void* d_ws, size_t ws_size,
                              hipStream_t stream)
{
    const float* x     = (const float*)d_in[0];
    const int*   ei    = (const int*)d_in[1];
    const int*   ts    = (const int*)d_in[2];
    const float* Wt    = (const float*)d_in[3];
    const float* Wl0   = (const float*)d_in[4];
    const float* bl0   = (const float*)d_in[5];
    const float* Wr0   = (const float*)d_in[6];
    const float* br0   = (const float*)d_in[7];
    const float* att0  = (const float*)d_in[8];
    const float* bias0 = (const float*)d_in[9];
    const float* Wl1   = (const float*)d_in[10];
    const float* bl1   = (const float*)d_in[11];
    const float* Wr1   = (const float*)d_in[12];
    const float* br1   = (const float*)d_in[13];
    const float* att1  = (const float*)d_in[14];
    const float* bias1 = (const float*)d_in[15];
    float* out = (float*)d_out;

    char* wsp = (char*)d_ws;
    size_t off = 0;
    auto alloc = [&](size_t bytes) -> void* {
        void* p = wsp + off;
        off += (bytes + 255) & ~(size_t)255;
        return p;
    };
    __half* xl0  = (__half*)alloc((size_t)NN * D1 * 2);
    __half* xr0  = (__half*)alloc((size_t)NN * D1 * 2);
    float* h1    = (float*)alloc((size_t)NN * D1 * 4);
    float* xl1   = (float*)alloc((size_t)NN * 2 * 4);
    float* xr1   = (float*)alloc((size_t)NN * 2 * 4);
    int* rowst   = (int*)alloc((size_t)(NN + 1) * 4);
    unsigned short* csr = (unsigned short*)alloc((size_t)EP * 2);
    int* gcnt        = (int*)alloc((size_t)NCB * 4);
    int* gbase       = (int*)alloc((size_t)NCB * 4);
    unsigned* cstage = (unsigned*)alloc((size_t)NCB * GCAP * 4);

    k_gemm0<<<2048, 256, 0, stream>>>(x, ts, Wt, Wl0, bl0, Wr0, br0, xl0, xr0);

    (void)hipMemsetAsync(gcnt, 0, (size_t)NCB * 4, stream);
    const int ntiles = (EP + TILE - 1) / TILE;
    k_part<<<ntiles, 1024, 0, stream>>>(ei, gcnt, cstage);
    k_cscan<<<1, 64, 0, stream>>>(gcnt, gbase, rowst);
    k_build2<<<NCB, 1024, 0, stream>>>(gcnt, gbase, cstage, rowst, csr);

    k_agg0<<<(NN + 3) / 4, 256, 0, stream>>>(rowst, csr, xl0, xr0, att0, bias0, h1);
    k_gemm1<<<(NN + 255) / 256, 256, 0, stream>>>(h1, Wl1, bl1, Wr1, br1, xl1, xr1);
    k_layer1<<<(NN + 255) / 256, 256, 0, stream>>>(rowst, csr, xl1, xr1, att1, bias1, out);
}

// Round 16
// 182.795 us; speedup vs baseline: 3.9860x; 1.0605x over previous
//
#include <hip/hip_runtime.h>
#include <hip/hip_fp16.h>

#define NN 50000
#define NE 1600000
#define EP (NE + NN)
#define INC 64
#define TDIM 32
#define INDIM 96
#define D1 128
#define NEG 0.2f

#define CBSH 9
#define NCB 98
#define GCAP 18432
#define TILE 8192

typedef _Float16 h2v __attribute__((ext_vector_type(2)));
union H2U { unsigned u; __half2 h; h2v v; };

__device__ __forceinline__ float lrelu(float v) { return v > 0.f ? v : NEG * v; }

// ---- GEMM0: 512 thr = (col, L/R, kslice); 48 weights/thread register-resident
__global__ __launch_bounds__(512, 2) void k_gemm0(
    const float* __restrict__ x, const int* __restrict__ ts,
    const float* __restrict__ Wt,
    const float* __restrict__ Wl, const float* __restrict__ bl,
    const float* __restrict__ Wr, const float* __restrict__ br,
    __half* __restrict__ xl0, __half* __restrict__ xr0)
{
    const int t = threadIdx.x;
    const int col = t & 127;
    const bool isR = (t & 128) != 0;
    const int kslice = t >> 8;
    const int k0 = kslice * 48;
    const float* __restrict__ W = isR ? Wr : Wl;
    float wreg[48];
#pragma unroll
    for (int k = 0; k < 48; ++k) wreg[k] = W[(k0 + k) * D1 + col];
    const float bias = (kslice == 0) ? (isR ? br[col] : bl[col]) : 0.f;

    __shared__ float hs[8][INDIM];
    __shared__ float part[8][512];
    const int tiles = (NN + 7) / 8;
    for (int tile = blockIdx.x; tile < tiles; tile += gridDim.x) {
        const int base = tile * 8;
        __syncthreads();
        for (int j = t; j < 8 * INDIM; j += 512) {
            int nd = j / INDIM;
            int k = j - nd * INDIM;
            int n = base + nd;
            float v = 0.f;
            if (n < NN)
                v = (k < INC) ? x[(size_t)n * INC + k]
                              : Wt[(size_t)ts[n] * TDIM + (k - INC)];
            hs[nd][k] = v;
        }
        __syncthreads();
        float acc[8];
#pragma unroll
        for (int nd = 0; nd < 8; ++nd) {
            const float4* hp = reinterpret_cast<const float4*>(&hs[nd][k0]);
            float a = 0.f, b = 0.f;
#pragma unroll
            for (int i = 0; i < 12; i += 2) {
                float4 h0 = hp[i];
                float4 h1 = hp[i + 1];
                a += wreg[4*i+0]*h0.x + wreg[4*i+1]*h0.y
                   + wreg[4*i+2]*h0.z + wreg[4*i+3]*h0.w;
                b += wreg[4*i+4]*h1.x + wreg[4*i+5]*h1.y
                   + wreg[4*i+6]*h1.z + wreg[4*i+7]*h1.w;
            }
            acc[nd] = a + b + bias;
        }
#pragma unroll
        for (int nd = 0; nd < 8; ++nd) part[nd][t] = acc[nd];
        __syncthreads();
        for (int idx = t; idx < 8 * 256; idx += 512) {
            int nd = idx >> 8;
            int o  = idx & 255;
            int n = base + nd;
            if (n < NN) {
                float r = part[nd][o] + part[nd][o + 256];
                __half* outp = (o & 128) ? xr0 : xl0;
                outp[(size_t)n * D1 + (o & 127)] = __float2half(r);
            }
        }
    }
}

// ---- pass A: LDS-staged coarse partition; coalesced flush into per-bucket runs
__global__ __launch_bounds__(1024) void k_part(
    const int* __restrict__ ei, int* __restrict__ gcnt, unsigned* __restrict__ cstage)
{
    __shared__ int cnt[NCB], loff[NCB + 1], gbasel[NCB], lpos[NCB];
    __shared__ unsigned pay[TILE];
    const int t = threadIdx.x;
    const int ntiles = (EP + TILE - 1) / TILE;
    for (int tile = blockIdx.x; tile < ntiles; tile += gridDim.x) {
        const int tb = tile * TILE;
        const int tc = min(TILE, EP - tb);
        if (t < NCB) cnt[t] = 0;
        __syncthreads();
        unsigned pk0, pk1, pk2, pk3, pk4, pk5, pk6, pk7;
#define LOADK(K, PK)                                              \
        {   int i = t + (K) * 1024;                               \
            if (i < tc) {                                         \
                int e = tb + i; int s, d;                         \
                if (e < NE) { s = ei[e]; d = ei[NE + e]; }        \
                else        { s = e - NE; d = s; }                \
                PK = ((unsigned)d << 16) | (unsigned)s;           \
                atomicAdd(&cnt[d >> CBSH], 1);                    \
            } }
        LOADK(0, pk0) LOADK(1, pk1) LOADK(2, pk2) LOADK(3, pk3)
        LOADK(4, pk4) LOADK(5, pk5) LOADK(6, pk6) LOADK(7, pk7)
#undef LOADK
        __syncthreads();
        if (t == 0) {
            int run = 0;
            for (int b = 0; b < NCB; ++b) { loff[b] = run; run += cnt[b]; }
            loff[NCB] = run;
        }
        __syncthreads();
        if (t < NCB) {
            gbasel[t] = atomicAdd(&gcnt[t], cnt[t]);
            lpos[t] = loff[t];
        }
        __syncthreads();
#define PLACEK(K, PK)                                             \
        {   int i = t + (K) * 1024;                               \
            if (i < tc) {                                         \
                int cb = (int)(PK >> (16 + CBSH));                \
                int p = atomicAdd(&lpos[cb], 1);                  \
                pay[p] = PK;                                      \
            } }
        PLACEK(0, pk0) PLACEK(1, pk1) PLACEK(2, pk2) PLACEK(3, pk3)
        PLACEK(4, pk4) PLACEK(5, pk5) PLACEK(6, pk6) PLACEK(7, pk7)
#undef PLACEK
        __syncthreads();
        for (int j = t; j < tc; j += 1024) {
            int lo = 0, hi = NCB - 1;
            while (lo < hi) { int mid = (lo + hi + 1) >> 1;
                              if (loff[mid] <= j) lo = mid; else hi = mid - 1; }
            int pos = gbasel[lo] + (j - loff[lo]);
            if (pos < GCAP) cstage[(size_t)lo * GCAP + pos] = pay[j];
        }
        __syncthreads();
    }
}

// ---- tiny scan over coarse buckets
__global__ void k_cscan(const int* __restrict__ gcnt, int* __restrict__ gbase,
                        int* __restrict__ rowst)
{
    if (threadIdx.x == 0) {
        int run = 0;
        for (int b = 0; b < NCB; ++b) { gbase[b] = run; run += min(gcnt[b], GCAP); }
        rowst[NN] = run;
    }
}

// ---- pass B: per coarse bucket: 512-dst LDS hist -> rowst; scatter u16 src
__global__ __launch_bounds__(1024) void k_build2(
    const int* __restrict__ gcnt, const int* __restrict__ gbase,
    const unsigned* __restrict__ cstage,
    int* __restrict__ rowst, unsigned short* __restrict__ csr)
{
    const int b = blockIdx.x;
    const int t = threadIdx.x;
    __shared__ int hist[512], sc[512], curs[512];
    const int cnt = min(gcnt[b], GCAP);
    const int base = gbase[b];
    const int d0 = b << CBSH;
    const int nd = min(512, NN - d0);
    if (t < 512) hist[t] = 0;
    __syncthreads();
    const unsigned* __restrict__ src = cstage + (size_t)b * GCAP;
    for (int i = t; i < cnt; i += 1024)
        atomicAdd(&hist[(src[i] >> 16) & 511], 1);
    __syncthreads();
    if (t < 512) sc[t] = hist[t];
    __syncthreads();
    for (int off = 1; off < 512; off <<= 1) {
        int v = 0;
        if (t < 512 && t >= off) v = sc[t - off];
        __syncthreads();
        if (t < 512) sc[t] += v;
        __syncthreads();
    }
    if (t < 512) {
        int excl = sc[t] - hist[t];
        curs[t] = excl;
        if (t < nd) rowst[d0 + t] = base + excl;
    }
    __syncthreads();
    for (int i = t; i < cnt; i += 1024) {
        unsigned v = src[i];
        int p = atomicAdd(&curs[(v >> 16) & 511], 1);
        csr[base + p] = (unsigned short)(v & 0xFFFFu);
    }
}

// ---- layer-0 fused: 4 edges/wave (slot = lane>>4), 8 fp16 channels/lane (uint4 gather)
__global__ __launch_bounds__(256) void k_agg0(
    const int* __restrict__ rowst, const unsigned short* __restrict__ csr,
    const __half* __restrict__ xl0, const __half* __restrict__ xr0,
    const float* __restrict__ att0, const float* __restrict__ bias0,
    float* __restrict__ h1)
{
    const int d = (blockIdx.x * 256 + threadIdx.x) >> 6;
    const int lane = threadIdx.x & 63;
    if (d >= NN) return;
    const int slot  = lane >> 4;          // 0..3: which edge of the quad
    const int lane4 = lane & 15;
    const int c0 = lane4 * 8;             // 8 channels (head = lane4>>2)

    uint4 xrw = *reinterpret_cast<const uint4*>(xr0 + (size_t)d * D1 + c0);
    H2U xr01, xr23, xr45, xr67;
    xr01.u = xrw.x; xr23.u = xrw.y; xr45.u = xrw.z; xr67.u = xrw.w;
    float4 atf0 = *reinterpret_cast<const float4*>(att0 + c0);
    float4 atf1 = *reinterpret_cast<const float4*>(att0 + c0 + 4);
    H2U at01, at23, at45, at67;
    at01.h = __floats2half2_rn(atf0.x, atf0.y);
    at23.h = __floats2half2_rn(atf0.z, atf0.w);
    at45.h = __floats2half2_rn(atf1.x, atf1.y);
    at67.h = __floats2half2_rn(atf1.z, atf1.w);
    const _Float16 kneg = (_Float16)NEG;
    const h2v k2 = { kneg, kneg };

    const int rs = rowst[d];
    const int cnt = rowst[d + 1] - rs;
    float acc0=0.f, acc1=0.f, acc2=0.f, acc3=0.f;
    float acc4=0.f, acc5=0.f, acc6=0.f, acc7=0.f, wsum=0.f;

#define EDGE(W, VALID)                                                      \
    {   H2U x01, x23, x45, x67;                                             \
        x01.u = (W).x; x23.u = (W).y; x45.u = (W).z; x67.u = (W).w;         \
        h2v s01 = x01.v + xr01.v, s23 = x23.v + xr23.v;                     \
        h2v s45 = x45.v + xr45.v, s67 = x67.v + xr67.v;                     \
        h2v l01 = __builtin_elementwise_max(s01, s01 * k2);                 \
        h2v l23 = __builtin_elementwise_max(s23, s23 * k2);                 \
        h2v l45 = __builtin_elementwise_max(s45, s45 * k2);                 \
        h2v l67 = __builtin_elementwise_max(s67, s67 * k2);                 \
        float p = __builtin_amdgcn_fdot2(l01, at01.v,                       \
                  __builtin_amdgcn_fdot2(l23, at23.v,                       \
                  __builtin_amdgcn_fdot2(l45, at45.v,                       \
                  __builtin_amdgcn_fdot2(l67, at67.v, 0.f, false),          \
                  false), false), false);                                   \
        p += __shfl_xor(p, 1);                                              \
        p += __shfl_xor(p, 2);          /* 4-lane (one head) reduce */      \
        float wgt = (VALID) ? __expf(p) : 0.f;                              \
        float2 f01 = __half22float2(x01.h), f23 = __half22float2(x23.h);    \
        float2 f45 = __half22float2(x45.h), f67 = __half22float2(x67.h);    \
        wsum += wgt;                                                        \
        acc0 += wgt * f01.x; acc1 += wgt * f01.y;                           \
        acc2 += wgt * f23.x; acc3 += wgt * f23.y;                           \
        acc4 += wgt * f45.x; acc5 += wgt * f45.y;                           \
        acc6 += wgt * f67.x; acc7 += wgt * f67.y;                           \
    }

    int i = 0;
    for (; i + 8 <= cnt; i += 8) {
        int s0 = csr[rs + i + slot];
        int s1 = csr[rs + i + 4 + slot];
        uint4 w0 = *reinterpret_cast<const uint4*>(xl0 + (size_t)s0 * D1 + c0);
        uint4 w1 = *reinterpret_cast<const uint4*>(xl0 + (size_t)s1 * D1 + c0);
        EDGE(w0, true);
        EDGE(w1, true);
    }
    for (; i < cnt; i += 4) {
        int e = i + slot;
        bool valid = (e < cnt);
        int s = csr[rs + (valid ? e : 0)];
        uint4 w = *reinterpret_cast<const uint4*>(xl0 + (size_t)s * D1 + c0);
        EDGE(w, valid);
    }
#undef EDGE

    // combine the four edge-slots (lane bits 4,5)
#define COMB(V) V += __shfl_xor(V, 16); V += __shfl_xor(V, 32);
    COMB(acc0) COMB(acc1) COMB(acc2) COMB(acc3)
    COMB(acc4) COMB(acc5) COMB(acc6) COMB(acc7)
    COMB(wsum)
#undef COMB

    if (slot == 0) {
        float r = 1.f / (wsum + 1e-16f);
        float4 b0 = *reinterpret_cast<const float4*>(bias0 + c0);
        float4 b1 = *reinterpret_cast<const float4*>(bias0 + c0 + 4);
        float4 o0, o1;
        o0.x = fmaxf(acc0 * r + b0.x, 0.f);
        o0.y = fmaxf(acc1 * r + b0.y, 0.f);
        o0.z = fmaxf(acc2 * r + b0.z, 0.f);
        o0.w = fmaxf(acc3 * r + b0.w, 0.f);
        o1.x = fmaxf(acc4 * r + b1.x, 0.f);
        o1.y = fmaxf(acc5 * r + b1.y, 0.f);
        o1.z = fmaxf(acc6 * r + b1.z, 0.f);
        o1.w = fmaxf(acc7 * r + b1.w, 0.f);
        *reinterpret_cast<float4*>(h1 + (size_t)d * D1 + c0)     = o0;
        *reinterpret_cast<float4*>(h1 + (size_t)d * D1 + c0 + 4) = o1;
    }
}

// ---- GEMM1: xl1 = h1@Wl1+bl1 ; xr1 = h1@Wr1+br1   (thread per node)
__global__ __launch_bounds__(256) void k_gemm1(
    const float* __restrict__ h1,
    const float* __restrict__ Wl, const float* __restrict__ bl,
    const float* __restrict__ Wr, const float* __restrict__ br,
    float* __restrict__ xl1, float* __restrict__ xr1)
{
    __shared__ float wls[D1 * 2], wrs[D1 * 2];
    const int t = threadIdx.x;
    wls[t] = Wl[t]; wrs[t] = Wr[t];
    __syncthreads();
    int n = blockIdx.x * 256 + t;
    if (n >= NN) return;
    float al0 = bl[0], al1 = bl[1], ar0 = br[0], ar1 = br[1];
    const float4* hp = reinterpret_cast<const float4*>(h1 + (size_t)n * D1);
    const float2* wl2 = reinterpret_cast<const float2*>(wls);
    const float2* wr2 = reinterpret_cast<const float2*>(wrs);
#pragma unroll
    for (int k4 = 0; k4 < D1 / 4; ++k4) {
        float4 hv = hp[k4];
        int k = k4 * 4;
        float2 a, b;
        a = wl2[k+0]; b = wr2[k+0]; al0 += hv.x*a.x; al1 += hv.x*a.y; ar0 += hv.x*b.x; ar1 += hv.x*b.y;
        a = wl2[k+1]; b = wr2[k+1]; al0 += hv.y*a.x; al1 += hv.y*a.y; ar0 += hv.y*b.x; ar1 += hv.y*b.y;
        a = wl2[k+2]; b = wr2[k+2]; al0 += hv.z*a.x; al1 += hv.z*a.y; ar0 += hv.z*b.x; ar1 += hv.z*b.y;
        a = wl2[k+3]; b = wr2[k+3]; al0 += hv.w*a.x; al1 += hv.w*a.y; ar0 += hv.w*b.x; ar1 += hv.w*b.y;
    }
    *reinterpret_cast<float2*>(xl1 + (size_t)n * 2) = make_float2(al0, al1);
    *reinterpret_cast<float2*>(xr1 + (size_t)n * 2) = make_float2(ar0, ar1);
}

// ---- layer-1 fused: thread per dst; 4-deep pipelined gather, normalize at end
__global__ __launch_bounds__(256) void k_layer1(
    const int* __restrict__ rowst, const unsigned short* __restrict__ csr,
    const float* __restrict__ xl1, const float* __restrict__ xr1,
    const float* __restrict__ att1, const float* __restrict__ bias1,
    float* __restrict__ out)
{
    int d = blockIdx.x * 256 + threadIdx.x;
    if (d >= NN) return;
    float2 xr = *reinterpret_cast<const float2*>(xr1 + (size_t)d * 2);
    float A0 = att1[0], A1 = att1[1];
    int rs = rowst[d], re = rowst[d + 1];
    float sum = 0.f, a0 = 0.f, a1 = 0.f;
    int i = rs;
    for (; i + 4 <= re; i += 4) {
        int s0 = csr[i], s1 = csr[i+1], s2 = csr[i+2], s3 = csr[i+3];
        float2 x0 = *reinterpret_cast<const float2*>(xl1 + (size_t)s0 * 2);
        float2 x1 = *reinterpret_cast<const float2*>(xl1 + (size_t)s1 * 2);
        float2 x2 = *reinterpret_cast<const float2*>(xl1 + (size_t)s2 * 2);
        float2 x3 = *reinterpret_cast<const float2*>(xl1 + (size_t)s3 * 2);
        float w0 = __expf(lrelu(x0.x + xr.x) * A0 + lrelu(x0.y + xr.y) * A1);
        float w1 = __expf(lrelu(x1.x + xr.x) * A0 + lrelu(x1.y + xr.y) * A1);
        float w2 = __expf(lrelu(x2.x + xr.x) * A0 + lrelu(x2.y + xr.y) * A1);
        float w3 = __expf(lrelu(x3.x + xr.x) * A0 + lrelu(x3.y + xr.y) * A1);
        sum += w0 + w1 + w2 + w3;
        a0 += w0 * x0.x + w1 * x1.x + w2 * x2.x + w3 * x3.x;
        a1 += w0 * x0.y + w1 * x1.y + w2 * x2.y + w3 * x3.y;
    }
    for (; i < re; ++i) {
        int s = csr[i];
        float2 xs = *reinterpret_cast<const float2*>(xl1 + (size_t)s * 2);
        float wgt = __expf(lrelu(xs.x + xr.x) * A0 + lrelu(xs.y + xr.y) * A1);
        sum += wgt;
        a0 += wgt * xs.x;
        a1 += wgt * xs.y;
    }
    float r = 1.f / (sum + 1e-16f);
    out[(size_t)d * 2]     = a0 * r + bias1[0];
    out[(size_t)d * 2 + 1] = a1 * r + bias1[1];
}

extern "C" void kernel_launch(void* const* d_in, const int* in_sizes, int n_in,
                              void* d_out, int out_size, void* d_ws, size_t ws_size,
                              hipStream_t stream)
{
    const float* x     = (const float*)d_in[0];
    const int*   ei    = (const int*)d_in[1];
    const int*   ts    = (const int*)d_in[2];
    const float* Wt    = (const float*)d_in[3];
    const float* Wl0   = (const float*)d_in[4];
    const float* bl0   = (const float*)d_in[5];
    const float* Wr0   = (const float*)d_in[6];
    const float* br0   = (const float*)d_in[7];
    const float* att0  = (const float*)d_in[8];
    const float* bias0 = (const float*)d_in[9];
    const float* Wl1   = (const float*)d_in[10];
    const float* bl1   = (const float*)d_in[11];
    const float* Wr1   = (const float*)d_in[12];
    const float* br1   = (const float*)d_in[13];
    const float* att1  = (const float*)d_in[14];
    const float* bias1 = (const float*)d_in[15];
    float* out = (float*)d_out;

    char* wsp = (char*)d_ws;
    size_t off = 0;
    auto alloc = [&](size_t bytes) -> void* {
        void* p = wsp + off;
        off += (bytes + 255) & ~(size_t)255;
        return p;
    };
    __half* xl0  = (__half*)alloc((size_t)NN * D1 * 2);
    __half* xr0  = (__half*)alloc((size_t)NN * D1 * 2);
    float* h1    = (float*)alloc((size_t)NN * D1 * 4);
    float* xl1   = (float*)alloc((size_t)NN * 2 * 4);
    float* xr1   = (float*)alloc((size_t)NN * 2 * 4);
    int* rowst   = (int*)alloc((size_t)(NN + 1) * 4);
    unsigned short* csr = (unsigned short*)alloc((size_t)EP * 2);
    int* gcnt        = (int*)alloc((size_t)NCB * 4);
    int* gbase       = (int*)alloc((size_t)NCB * 4);
    unsigned* cstage = (unsigned*)alloc((size_t)NCB * GCAP * 4);

    k_gemm0<<<2048, 512, 0, stream>>>(x, ts, Wt, Wl0, bl0, Wr0, br0, xl0, xr0);

    (void)hipMemsetAsync(gcnt, 0, (size_t)NCB * 4, stream);
    const int ntiles = (EP + TILE - 1) / TILE;
    k_part<<<ntiles, 1024, 0, stream>>>(ei, gcnt, cstage);
    k_cscan<<<1, 64, 0, stream>>>(gcnt, gbase, rowst);
    k_build2<<<NCB, 1024, 0, stream>>>(gcnt, gbase, cstage, rowst, csr);

    k_agg0<<<(NN + 3) / 4, 256, 0, stream>>>(rowst, csr, xl0, xr0, att0, bias0, h1);
    k_gemm1<<<(NN + 255) / 256, 256, 0, stream>>>(h1, Wl1, bl1, Wr1, br1, xl1, xr1);
    k_layer1<<<(NN + 255) / 256, 256, 0, stream>>>(rowst, csr, xl1, xr1, att1, bias1, out);
}

// Round 17
// 178.126 us; speedup vs baseline: 4.0905x; 1.0262x over previous
//
#include <hip/hip_runtime.h>
#include <hip/hip_fp16.h>

#define NN 50000
#define NE 1600000
#define EP (NE + NN)
#define INC 64
#define TDIM 32
#define INDIM 96
#define D1 128
#define NEG 0.2f

#define CBSH 9
#define NCB 98
#define GCAP 18432
#define TILE 8192

#define MT 64                 // gemm0 M-tile rows per block
#define KP 104                // padded K stride (208B rows, 16B aligned)

typedef _Float16 h2v __attribute__((ext_vector_type(2)));
typedef _Float16 f16x8 __attribute__((ext_vector_type(8)));
typedef float f32x4 __attribute__((ext_vector_type(4)));
union H2U { unsigned u; __half2 h; h2v v; };

__device__ __forceinline__ float lrelu(float v) { return v > 0.f ? v : NEG * v; }

// ---- pack Wl|Wr into transposed fp16 B [256][96] + bias concat [256]
__global__ __launch_bounds__(256) void k_wcast(
    const float* __restrict__ Wl, const float* __restrict__ Wr,
    const float* __restrict__ bl, const float* __restrict__ br,
    __half* __restrict__ Btg, float* __restrict__ bcat)
{
    int idx = blockIdx.x * 256 + threadIdx.x;
    if (idx < 256) bcat[idx] = (idx < 128) ? bl[idx] : br[idx - 128];
    if (idx >= 256 * INDIM) return;
    int c = idx / INDIM, k = idx - c * INDIM;
    float v = (c < 128) ? Wl[k * D1 + c] : Wr[k * D1 + (c - 128)];
    Btg[idx] = __float2half(v);
}

// ---- GEMM0 via MFMA: [64 nodes x 96] fp16 @ [96 x 256] fp16 -> xl0|xr0 fp16
__global__ __launch_bounds__(256) void k_gemm0m(
    const float* __restrict__ x, const int* __restrict__ ts,
    const float* __restrict__ Wt,
    const __half* __restrict__ Btg, const float* __restrict__ bcat,
    __half* __restrict__ xl0, __half* __restrict__ xr0)
{
    __shared__ _Float16 As[MT][KP];
    __shared__ _Float16 Bs[256][KP];
    const int t = threadIdx.x;
    const int base = blockIdx.x * MT;

    // stage B: 256 cols x 12 k-groups of 8 halfs (16B)
    for (int f = t; f < 256 * 12; f += 256) {
        int c = f / 12, kg = f - c * 12;
        uint4 v = *reinterpret_cast<const uint4*>(Btg + c * INDIM + kg * 8);
        *reinterpret_cast<uint4*>(&Bs[c][kg * 8]) = v;
    }
    // stage A: h rows (x | Wt[ts]) cast fp16
    for (int f = t; f < MT * INDIM; f += 256) {
        int m = f / INDIM, k = f - m * INDIM;
        int n = base + m;
        float v = 0.f;
        if (n < NN)
            v = (k < INC) ? x[(size_t)n * INC + k]
                          : Wt[(size_t)ts[n] * TDIM + (k - INC)];
        As[m][k] = (_Float16)v;
    }
    __syncthreads();

    const int lane = t & 63;
    const int w = t >> 6;            // wave id: N range [w*64, w*64+64)
    const int lo4 = lane & 15;
    const int hi2 = lane >> 4;

    f32x4 acc[4][4] = {};
#pragma unroll
    for (int ks = 0; ks < 3; ++ks) {
        const int kb = ks * 32 + hi2 * 8;
        f16x8 a[4], b[4];
#pragma unroll
        for (int ms = 0; ms < 4; ++ms)
            a[ms] = *reinterpret_cast<const f16x8*>(&As[ms * 16 + lo4][kb]);
#pragma unroll
        for (int ns = 0; ns < 4; ++ns)
            b[ns] = *reinterpret_cast<const f16x8*>(&Bs[w * 64 + ns * 16 + lo4][kb]);
#pragma unroll
        for (int ms = 0; ms < 4; ++ms)
#pragma unroll
            for (int ns = 0; ns < 4; ++ns)
                acc[ms][ns] = __builtin_amdgcn_mfma_f32_16x16x32_f16(
                    a[ms], b[ns], acc[ms][ns], 0, 0, 0);
    }

#pragma unroll
    for (int ms = 0; ms < 4; ++ms) {
#pragma unroll
        for (int ns = 0; ns < 4; ++ns) {
            int col = w * 64 + ns * 16 + lo4;
            float bv = bcat[col];
            __half* outp = (col & 128) ? xr0 : xl0;
            int cc = col & 127;
#pragma unroll
            for (int r = 0; r < 4; ++r) {
                int node = base + ms * 16 + hi2 * 4 + r;
                if (node < NN)
                    outp[(size_t)node * D1 + cc] = __float2half(acc[ms][ns][r] + bv);
            }
        }
    }
}

// ---- pass A: LDS-staged coarse partition; coalesced flush into per-bucket runs
__global__ __launch_bounds__(1024) void k_part(
    const int* __restrict__ ei, int* __restrict__ gcnt, unsigned* __restrict__ cstage)
{
    __shared__ int cnt[NCB], loff[NCB + 1], gbasel[NCB], lpos[NCB];
    __shared__ unsigned pay[TILE];
    const int t = threadIdx.x;
    const int ntiles = (EP + TILE - 1) / TILE;
    for (int tile = blockIdx.x; tile < ntiles; tile += gridDim.x) {
        const int tb = tile * TILE;
        const int tc = min(TILE, EP - tb);
        if (t < NCB) cnt[t] = 0;
        __syncthreads();
        unsigned pk0, pk1, pk2, pk3, pk4, pk5, pk6, pk7;
#define LOADK(K, PK)                                              \
        {   int i = t + (K) * 1024;                               \
            if (i < tc) {                                         \
                int e = tb + i; int s, d;                         \
                if (e < NE) { s = ei[e]; d = ei[NE + e]; }        \
                else        { s = e - NE; d = s; }                \
                PK = ((unsigned)d << 16) | (unsigned)s;           \
                atomicAdd(&cnt[d >> CBSH], 1);                    \
            } }
        LOADK(0, pk0) LOADK(1, pk1) LOADK(2, pk2) LOADK(3, pk3)
        LOADK(4, pk4) LOADK(5, pk5) LOADK(6, pk6) LOADK(7, pk7)
#undef LOADK
        __syncthreads();
        if (t == 0) {
            int run = 0;
            for (int b = 0; b < NCB; ++b) { loff[b] = run; run += cnt[b]; }
            loff[NCB] = run;
        }
        __syncthreads();
        if (t < NCB) {
            gbasel[t] = atomicAdd(&gcnt[t], cnt[t]);
            lpos[t] = loff[t];
        }
        __syncthreads();
#define PLACEK(K, PK)                                             \
        {   int i = t + (K) * 1024;                               \
            if (i < tc) {                                         \
                int cb = (int)(PK >> (16 + CBSH));                \
                int p = atomicAdd(&lpos[cb], 1);                  \
                pay[p] = PK;                                      \
            } }
        PLACEK(0, pk0) PLACEK(1, pk1) PLACEK(2, pk2) PLACEK(3, pk3)
        PLACEK(4, pk4) PLACEK(5, pk5) PLACEK(6, pk6) PLACEK(7, pk7)
#undef PLACEK
        __syncthreads();
        for (int j = t; j < tc; j += 1024) {
            int lo = 0, hi = NCB - 1;
            while (lo < hi) { int mid = (lo + hi + 1) >> 1;
                              if (loff[mid] <= j) lo = mid; else hi = mid - 1; }
            int pos = gbasel[lo] + (j - loff[lo]);
            if (pos < GCAP) cstage[(size_t)lo * GCAP + pos] = pay[j];
        }
        __syncthreads();
    }
}

// ---- tiny scan over coarse buckets
__global__ void k_cscan(const int* __restrict__ gcnt, int* __restrict__ gbase,
                        int* __restrict__ rowst)
{
    if (threadIdx.x == 0) {
        int run = 0;
        for (int b = 0; b < NCB; ++b) { gbase[b] = run; run += min(gcnt[b], GCAP); }
        rowst[NN] = run;
    }
}

// ---- pass B: per coarse bucket: 512-dst LDS hist -> rowst; scatter u16 src
__global__ __launch_bounds__(1024) void k_build2(
    const int* __restrict__ gcnt, const int* __restrict__ gbase,
    const unsigned* __restrict__ cstage,
    int* __restrict__ rowst, unsigned short* __restrict__ csr)
{
    const int b = blockIdx.x;
    const int t = threadIdx.x;
    __shared__ int hist[512], sc[512], curs[512];
    const int cnt = min(gcnt[b], GCAP);
    const int base = gbase[b];
    const int d0 = b << CBSH;
    const int nd = min(512, NN - d0);
    if (t < 512) hist[t] = 0;
    __syncthreads();
    const unsigned* __restrict__ src = cstage + (size_t)b * GCAP;
    for (int i = t; i < cnt; i += 1024)
        atomicAdd(&hist[(src[i] >> 16) & 511], 1);
    __syncthreads();
    if (t < 512) sc[t] = hist[t];
    __syncthreads();
    for (int off = 1; off < 512; off <<= 1) {
        int v = 0;
        if (t < 512 && t >= off) v = sc[t - off];
        __syncthreads();
        if (t < 512) sc[t] += v;
        __syncthreads();
    }
    if (t < 512) {
        int excl = sc[t] - hist[t];
        curs[t] = excl;
        if (t < nd) rowst[d0 + t] = base + excl;
    }
    __syncthreads();
    for (int i = t; i < cnt; i += 1024) {
        unsigned v = src[i];
        int p = atomicAdd(&curs[(v >> 16) & 511], 1);
        csr[base + p] = (unsigned short)(v & 0xFFFFu);
    }
}

// ---- layer-0 fused: 4 edges/wave (slot = lane>>4), 8 fp16 channels/lane (uint4 gather)
__global__ __launch_bounds__(256) void k_agg0(
    const int* __restrict__ rowst, const unsigned short* __restrict__ csr,
    const __half* __restrict__ xl0, const __half* __restrict__ xr0,
    const float* __restrict__ att0, const float* __restrict__ bias0,
    float* __restrict__ h1)
{
    const int d = (blockIdx.x * 256 + threadIdx.x) >> 6;
    const int lane = threadIdx.x & 63;
    if (d >= NN) return;
    const int slot  = lane >> 4;
    const int lane4 = lane & 15;
    const int c0 = lane4 * 8;

    uint4 xrw = *reinterpret_cast<const uint4*>(xr0 + (size_t)d * D1 + c0);
    H2U xr01, xr23, xr45, xr67;
    xr01.u = xrw.x; xr23.u = xrw.y; xr45.u = xrw.z; xr67.u = xrw.w;
    float4 atf0 = *reinterpret_cast<const float4*>(att0 + c0);
    float4 atf1 = *reinterpret_cast<const float4*>(att0 + c0 + 4);
    H2U at01, at23, at45, at67;
    at01.h = __floats2half2_rn(atf0.x, atf0.y);
    at23.h = __floats2half2_rn(atf0.z, atf0.w);
    at45.h = __floats2half2_rn(atf1.x, atf1.y);
    at67.h = __floats2half2_rn(atf1.z, atf1.w);
    const _Float16 kneg = (_Float16)NEG;
    const h2v k2 = { kneg, kneg };

    const int rs = rowst[d];
    const int cnt = rowst[d + 1] - rs;
    float acc0=0.f, acc1=0.f, acc2=0.f, acc3=0.f;
    float acc4=0.f, acc5=0.f, acc6=0.f, acc7=0.f, wsum=0.f;

#define EDGE(W, VALID)                                                      \
    {   H2U x01, x23, x45, x67;                                             \
        x01.u = (W).x; x23.u = (W).y; x45.u = (W).z; x67.u = (W).w;         \
        h2v s01 = x01.v + xr01.v, s23 = x23.v + xr23.v;                     \
        h2v s45 = x45.v + xr45.v, s67 = x67.v + xr67.v;                     \
        h2v l01 = __builtin_elementwise_max(s01, s01 * k2);                 \
        h2v l23 = __builtin_elementwise_max(s23, s23 * k2);                 \
        h2v l45 = __builtin_elementwise_max(s45, s45 * k2);                 \
        h2v l67 = __builtin_elementwise_max(s67, s67 * k2);                 \
        float p = __builtin_amdgcn_fdot2(l01, at01.v,                       \
                  __builtin_amdgcn_fdot2(l23, at23.v,                       \
                  __builtin_amdgcn_fdot2(l45, at45.v,                       \
                  __builtin_amdgcn_fdot2(l67, at67.v, 0.f, false),          \
                  false), false), false);                                   \
        p += __shfl_xor(p, 1);                                              \
        p += __shfl_xor(p, 2);                                              \
        float wgt = (VALID) ? __expf(p) : 0.f;                              \
        float2 f01 = __half22float2(x01.h), f23 = __half22float2(x23.h);    \
        float2 f45 = __half22float2(x45.h), f67 = __half22float2(x67.h);    \
        wsum += wgt;                                                        \
        acc0 += wgt * f01.x; acc1 += wgt * f01.y;                           \
        acc2 += wgt * f23.x; acc3 += wgt * f23.y;                           \
        acc4 += wgt * f45.x; acc5 += wgt * f45.y;                           \
        acc6 += wgt * f67.x; acc7 += wgt * f67.y;                           \
    }

    int i = 0;
    for (; i + 8 <= cnt; i += 8) {
        int s0 = csr[rs + i + slot];
        int s1 = csr[rs + i + 4 + slot];
        uint4 w0 = *reinterpret_cast<const uint4*>(xl0 + (size_t)s0 * D1 + c0);
        uint4 w1 = *reinterpret_cast<const uint4*>(xl0 + (size_t)s1 * D1 + c0);
        EDGE(w0, true);
        EDGE(w1, true);
    }
    for (; i < cnt; i += 4) {
        int e = i + slot;
        bool valid = (e < cnt);
        int s = csr[rs + (valid ? e : 0)];
        uint4 w = *reinterpret_cast<const uint4*>(xl0 + (size_t)s * D1 + c0);
        EDGE(w, valid);
    }
#undef EDGE

#define COMB(V) V += __shfl_xor(V, 16); V += __shfl_xor(V, 32);
    COMB(acc0) COMB(acc1) COMB(acc2) COMB(acc3)
    COMB(acc4) COMB(acc5) COMB(acc6) COMB(acc7)
    COMB(wsum)
#undef COMB

    if (slot == 0) {
        float r = 1.f / (wsum + 1e-16f);
        float4 b0 = *reinterpret_cast<const float4*>(bias0 + c0);
        float4 b1 = *reinterpret_cast<const float4*>(bias0 + c0 + 4);
        float4 o0, o1;
        o0.x = fmaxf(acc0 * r + b0.x, 0.f);
        o0.y = fmaxf(acc1 * r + b0.y, 0.f);
        o0.z = fmaxf(acc2 * r + b0.z, 0.f);
        o0.w = fmaxf(acc3 * r + b0.w, 0.f);
        o1.x = fmaxf(acc4 * r + b1.x, 0.f);
        o1.y = fmaxf(acc5 * r + b1.y, 0.f);
        o1.z = fmaxf(acc6 * r + b1.z, 0.f);
        o1.w = fmaxf(acc7 * r + b1.w, 0.f);
        *reinterpret_cast<float4*>(h1 + (size_t)d * D1 + c0)     = o0;
        *reinterpret_cast<float4*>(h1 + (size_t)d * D1 + c0 + 4) = o1;
    }
}

// ---- GEMM1: xl1 = h1@Wl1+bl1 ; xr1 = h1@Wr1+br1   (thread per node)
__global__ __launch_bounds__(256) void k_gemm1(
    const float* __restrict__ h1,
    const float* __restrict__ Wl, const float* __restrict__ bl,
    const float* __restrict__ Wr, const float* __restrict__ br,
    float* __restrict__ xl1, float* __restrict__ xr1)
{
    __shared__ float wls[D1 * 2], wrs[D1 * 2];
    const int t = threadIdx.x;
    wls[t] = Wl[t]; wrs[t] = Wr[t];
    __syncthreads();
    int n = blockIdx.x * 256 + t;
    if (n >= NN) return;
    float al0 = bl[0], al1 = bl[1], ar0 = br[0], ar1 = br[1];
    const float4* hp = reinterpret_cast<const float4*>(h1 + (size_t)n * D1);
    const float2* wl2 = reinterpret_cast<const float2*>(wls);
    const float2* wr2 = reinterpret_cast<const float2*>(wrs);
#pragma unroll
    for (int k4 = 0; k4 < D1 / 4; ++k4) {
        float4 hv = hp[k4];
        int k = k4 * 4;
        float2 a, b;
        a = wl2[k+0]; b = wr2[k+0]; al0 += hv.x*a.x; al1 += hv.x*a.y; ar0 += hv.x*b.x; ar1 += hv.x*b.y;
        a = wl2[k+1]; b = wr2[k+1]; al0 += hv.y*a.x; al1 += hv.y*a.y; ar0 += hv.y*b.x; ar1 += hv.y*b.y;
        a = wl2[k+2]; b = wr2[k+2]; al0 += hv.z*a.x; al1 += hv.z*a.y; ar0 += hv.z*b.x; ar1 += hv.z*b.y;
        a = wl2[k+3]; b = wr2[k+3]; al0 += hv.w*a.x; al1 += hv.w*a.y; ar0 += hv.w*b.x; ar1 += hv.w*b.y;
    }
    *reinterpret_cast<float2*>(xl1 + (size_t)n * 2) = make_float2(al0, al1);
    *reinterpret_cast<float2*>(xr1 + (size_t)n * 2) = make_float2(ar0, ar1);
}

// ---- layer-1 fused: thread per dst; 4-deep pipelined gather, normalize at end
__global__ __launch_bounds__(256) void k_layer1(
    const int* __restrict__ rowst, const unsigned short* __restrict__ csr,
    const float* __restrict__ xl1, const float* __restrict__ xr1,
    const float* __restrict__ att1, const float* __restrict__ bias1,
    float* __restrict__ out)
{
    int d = blockIdx.x * 256 + threadIdx.x;
    if (d >= NN) return;
    float2 xr = *reinterpret_cast<const float2*>(xr1 + (size_t)d * 2);
    float A0 = att1[0], A1 = att1[1];
    int rs = rowst[d], re = rowst[d + 1];
    float sum = 0.f, a0 = 0.f, a1 = 0.f;
    int i = rs;
    for (; i + 4 <= re; i += 4) {
        int s0 = csr[i], s1 = csr[i+1], s2 = csr[i+2], s3 = csr[i+3];
        float2 x0 = *reinterpret_cast<const float2*>(xl1 + (size_t)s0 * 2);
        float2 x1 = *reinterpret_cast<const float2*>(xl1 + (size_t)s1 * 2);
        float2 x2 = *reinterpret_cast<const float2*>(xl1 + (size_t)s2 * 2);
        float2 x3 = *reinterpret_cast<const float2*>(xl1 + (size_t)s3 * 2);
        float w0 = __expf(lrelu(x0.x + xr.x) * A0 + lrelu(x0.y + xr.y) * A1);
        float w1 = __expf(lrelu(x1.x + xr.x) * A0 + lrelu(x1.y + xr.y) * A1);
        float w2 = __expf(lrelu(x2.x + xr.x) * A0 + lrelu(x2.y + xr.y) * A1);
        float w3 = __expf(lrelu(x3.x + xr.x) * A0 + lrelu(x3.y + xr.y) * A1);
        sum += w0 + w1 + w2 + w3;
        a0 += w0 * x0.x + w1 * x1.x + w2 * x2.x + w3 * x3.x;
        a1 += w0 * x0.y + w1 * x1.y + w2 * x2.y + w3 * x3.y;
    }
    for (; i < re; ++i) {
        int s = csr[i];
        float2 xs = *reinterpret_cast<const float2*>(xl1 + (size_t)s * 2);
        float wgt = __expf(lrelu(xs.x + xr.x) * A0 + lrelu(xs.y + xr.y) * A1);
        sum += wgt;
        a0 += wgt * xs.x;
        a1 += wgt * xs.y;
    }
    float r = 1.f / (sum + 1e-16f);
    out[(size_t)d * 2]     = a0 * r + bias1[0];
    out[(size_t)d * 2 + 1] = a1 * r + bias1[1];
}

extern "C" void kernel_launch(void* const* d_in, const int* in_sizes, int n_in,
                              void* d_out, int out_size, void* d_ws, size_t ws_size,
                              hipStream_t stream)
{
    const float* x     = (const float*)d_in[0];
    const int*   ei    = (const int*)d_in[1];
    const int*   ts    = (const int*)d_in[2];
    const float* Wt    = (const float*)d_in[3];
    const float* Wl0   = (const float*)d_in[4];
    const float* bl0   = (const float*)d_in[5];
    const float* Wr0   = (const float*)d_in[6];
    const float* br0   = (const float*)d_in[7];
    const float* att0  = (const float*)d_in[8];
    const float* bias0 = (const float*)d_in[9];
    const float* Wl1   = (const float*)d_in[10];
    const float* bl1   = (const float*)d_in[11];
    const float* Wr1   = (const float*)d_in[12];
    const float* br1   = (const float*)d_in[13];
    const float* att1  = (const float*)d_in[14];
    const float* bias1 = (const float*)d_in[15];
    float* out = (float*)d_out;

    char* wsp = (char*)d_ws;
    size_t off = 0;
    auto alloc = [&](size_t bytes) -> void* {
        void* p = wsp + off;
        off += (bytes + 255) & ~(size_t)255;
        return p;
    };
    __half* xl0  = (__half*)alloc((size_t)NN * D1 * 2);
    __half* xr0  = (__half*)alloc((size_t)NN * D1 * 2);
    float* h1    = (float*)alloc((size_t)NN * D1 * 4);
    float* xl1   = (float*)alloc((size_t)NN * 2 * 4);
    float* xr1   = (float*)alloc((size_t)NN * 2 * 4);
    int* rowst   = (int*)alloc((size_t)(NN + 1) * 4);
    unsigned short* csr = (unsigned short*)alloc((size_t)EP * 2);
    int* gcnt        = (int*)alloc((size_t)NCB * 4);
    int* gbase       = (int*)alloc((size_t)NCB * 4);
    unsigned* cstage = (unsigned*)alloc((size_t)NCB * GCAP * 4);
    __half* Btg      = (__half*)alloc((size_t)256 * INDIM * 2);
    float* bcat      = (float*)alloc((size_t)256 * 4);

    k_wcast<<<(256 * INDIM + 255) / 256, 256, 0, stream>>>(Wl0, Wr0, bl0, br0, Btg, bcat);
    k_gemm0m<<<(NN + MT - 1) / MT, 256, 0, stream>>>(x, ts, Wt, Btg, bcat, xl0, xr0);

    (void)hipMemsetAsync(gcnt, 0, (size_t)NCB * 4, stream);
    const int ntiles = (EP + TILE - 1) / TILE;
    k_part<<<ntiles, 1024, 0, stream>>>(ei, gcnt, cstage);
    k_cscan<<<1, 64, 0, stream>>>(gcnt, gbase, rowst);
    k_build2<<<NCB, 1024, 0, stream>>>(gcnt, gbase, cstage, rowst, csr);

    k_agg0<<<(NN + 3) / 4, 256, 0, stream>>>(rowst, csr, xl0, xr0, att0, bias0, h1);
    k_gemm1<<<(NN + 255) / 256, 256, 0, stream>>>(h1, Wl1, bl1, Wr1, br1, xl1, xr1);
    k_layer1<<<(NN + 255) / 256, 256, 0, stream>>>(rowst, csr, xl1, xr1, att1, bias1, out);
}

// Round 18
// 154.521 us; speedup vs baseline: 4.7153x; 1.1528x over previous
//
#include <hip/hip_runtime.h>
#include <hip/hip_fp16.h>

#define NN 50000
#define NE 1600000
#define EP (NE + NN)
#define INC 64
#define TDIM 32
#define INDIM 96
#define D1 128
#define NEG 0.2f

#define CBSH 9
#define NCB 98
#define GCAP 18432
#define TILE 8192

#define MT 64                 // gemm0 M-tile rows per block
#define KP 104                // padded K stride (208B rows, 16B aligned)

typedef _Float16 h2v __attribute__((ext_vector_type(2)));
typedef _Float16 f16x8 __attribute__((ext_vector_type(8)));
typedef float f32x4 __attribute__((ext_vector_type(4)));
union H2U { unsigned u; __half2 h; h2v v; };

__device__ __forceinline__ float lrelu(float v) { return v > 0.f ? v : NEG * v; }

// ---- pack Wl|Wr into transposed fp16 B [256][96] + bias concat [256]
__global__ __launch_bounds__(256) void k_wcast(
    const float* __restrict__ Wl, const float* __restrict__ Wr,
    const float* __restrict__ bl, const float* __restrict__ br,
    __half* __restrict__ Btg, float* __restrict__ bcat)
{
    int idx = blockIdx.x * 256 + threadIdx.x;
    if (idx < 256) bcat[idx] = (idx < 128) ? bl[idx] : br[idx - 128];
    if (idx >= 256 * INDIM) return;
    int c = idx / INDIM, k = idx - c * INDIM;
    float v = (c < 128) ? Wl[k * D1 + c] : Wr[k * D1 + (c - 128)];
    Btg[idx] = __float2half(v);
}

// ---- GEMM0 via MFMA: A staged in LDS (13KB), B read from global (L2-resident)
__global__ __launch_bounds__(256) void k_gemm0m(
    const float* __restrict__ x, const int* __restrict__ ts,
    const float* __restrict__ Wt,
    const __half* __restrict__ Btg, const float* __restrict__ bcat,
    __half* __restrict__ xl0, __half* __restrict__ xr0)
{
    __shared__ _Float16 As[MT][KP];
    const int t = threadIdx.x;
    const int base = blockIdx.x * MT;
    const float4* __restrict__ x4  = reinterpret_cast<const float4*>(x);
    const float4* __restrict__ wt4 = reinterpret_cast<const float4*>(Wt);

    // phase 1: issue 6 independent float4 loads (64 rows x 24 float4-chunks)
    float4 av0, av1, av2, av3, av4, av5;
#define LOADA(J, AV)                                                   \
    {   int c = t + (J) * 256;                                         \
        int m = c / 24, q = c - m * 24;                                \
        int n = base + m;                                              \
        if (n < NN)                                                    \
            AV = (q < 16) ? x4[(size_t)n * 16 + q]                     \
                          : wt4[(size_t)ts[n] * 8 + (q - 16)];         \
        else AV = make_float4(0.f, 0.f, 0.f, 0.f);                     \
    }
    LOADA(0, av0) LOADA(1, av1) LOADA(2, av2)
    LOADA(3, av3) LOADA(4, av4) LOADA(5, av5)
#undef LOADA
    // phase 2: convert + LDS write
#define WRITEA(J, AV)                                                  \
    {   int c = t + (J) * 256;                                         \
        int m = c / 24, q = c - m * 24;                                \
        h2v p01 = { (_Float16)AV.x, (_Float16)AV.y };                  \
        h2v p23 = { (_Float16)AV.z, (_Float16)AV.w };                  \
        *reinterpret_cast<h2v*>(&As[m][q * 4])     = p01;              \
        *reinterpret_cast<h2v*>(&As[m][q * 4 + 2]) = p23;              \
    }
    WRITEA(0, av0) WRITEA(1, av1) WRITEA(2, av2)
    WRITEA(3, av3) WRITEA(4, av4) WRITEA(5, av5)
#undef WRITEA
    __syncthreads();

    const int lane = t & 63;
    const int w = t >> 6;            // wave id: N cols [w*64, w*64+64)
    const int lo4 = lane & 15;
    const int hi2 = lane >> 4;

    f32x4 acc[4][4] = {};
#pragma unroll
    for (int ks = 0; ks < 3; ++ks) {
        const int kb = ks * 32 + hi2 * 8;       // in halfs
        f16x8 a[4], b[4];
#pragma unroll
        for (int ns = 0; ns < 4; ++ns)
            b[ns] = *reinterpret_cast<const f16x8*>(
                Btg + (size_t)(w * 64 + ns * 16 + lo4) * INDIM + kb);
#pragma unroll
        for (int ms = 0; ms < 4; ++ms)
            a[ms] = *reinterpret_cast<const f16x8*>(&As[ms * 16 + lo4][kb]);
#pragma unroll
        for (int ms = 0; ms < 4; ++ms)
#pragma unroll
            for (int ns = 0; ns < 4; ++ns)
                acc[ms][ns] = __builtin_amdgcn_mfma_f32_16x16x32_f16(
                    a[ms], b[ns], acc[ms][ns], 0, 0, 0);
    }

#pragma unroll
    for (int ms = 0; ms < 4; ++ms) {
#pragma unroll
        for (int ns = 0; ns < 4; ++ns) {
            int col = w * 64 + ns * 16 + lo4;
            float bv = bcat[col];
            __half* outp = (col & 128) ? xr0 : xl0;
            int cc = col & 127;
#pragma unroll
            for (int r = 0; r < 4; ++r) {
                int node = base + ms * 16 + hi2 * 4 + r;
                if (node < NN)
                    outp[(size_t)node * D1 + cc] = __float2half(acc[ms][ns][r] + bv);
            }
        }
    }
}

// ---- pass A: LDS-staged coarse partition; coalesced flush into per-bucket runs
__global__ __launch_bounds__(1024) void k_part(
    const int* __restrict__ ei, int* __restrict__ gcnt, unsigned* __restrict__ cstage)
{
    __shared__ int cnt[NCB], loff[NCB + 1], gbasel[NCB], lpos[NCB];
    __shared__ unsigned pay[TILE];
    const int t = threadIdx.x;
    const int ntiles = (EP + TILE - 1) / TILE;
    for (int tile = blockIdx.x; tile < ntiles; tile += gridDim.x) {
        const int tb = tile * TILE;
        const int tc = min(TILE, EP - tb);
        if (t < NCB) cnt[t] = 0;
        __syncthreads();
        unsigned pk0, pk1, pk2, pk3, pk4, pk5, pk6, pk7;
#define LOADK(K, PK)                                              \
        {   int i = t + (K) * 1024;                               \
            if (i < tc) {                                         \
                int e = tb + i; int s, d;                         \
                if (e < NE) { s = ei[e]; d = ei[NE + e]; }        \
                else        { s = e - NE; d = s; }                \
                PK = ((unsigned)d << 16) | (unsigned)s;           \
                atomicAdd(&cnt[d >> CBSH], 1);                    \
            } }
        LOADK(0, pk0) LOADK(1, pk1) LOADK(2, pk2) LOADK(3, pk3)
        LOADK(4, pk4) LOADK(5, pk5) LOADK(6, pk6) LOADK(7, pk7)
#undef LOADK
        __syncthreads();
        if (t == 0) {
            int run = 0;
            for (int b = 0; b < NCB; ++b) { loff[b] = run; run += cnt[b]; }
            loff[NCB] = run;
        }
        __syncthreads();
        if (t < NCB) {
            gbasel[t] = atomicAdd(&gcnt[t], cnt[t]);
            lpos[t] = loff[t];
        }
        __syncthreads();
#define PLACEK(K, PK)                                             \
        {   int i = t + (K) * 1024;                               \
            if (i < tc) {                                         \
                int cb = (int)(PK >> (16 + CBSH));                \
                int p = atomicAdd(&lpos[cb], 1);                  \
                pay[p] = PK;                                      \
            } }
        PLACEK(0, pk0) PLACEK(1, pk1) PLACEK(2, pk2) PLACEK(3, pk3)
        PLACEK(4, pk4) PLACEK(5, pk5) PLACEK(6, pk6) PLACEK(7, pk7)
#undef PLACEK
        __syncthreads();
        for (int j = t; j < tc; j += 1024) {
            int lo = 0, hi = NCB - 1;
            while (lo < hi) { int mid = (lo + hi + 1) >> 1;
                              if (loff[mid] <= j) lo = mid; else hi = mid - 1; }
            int pos = gbasel[lo] + (j - loff[lo]);
            if (pos < GCAP) cstage[(size_t)lo * GCAP + pos] = pay[j];
        }
        __syncthreads();
    }
}

// ---- tiny scan over coarse buckets
__global__ void k_cscan(const int* __restrict__ gcnt, int* __restrict__ gbase,
                        int* __restrict__ rowst)
{
    if (threadIdx.x == 0) {
        int run = 0;
        for (int b = 0; b < NCB; ++b) { gbase[b] = run; run += min(gcnt[b], GCAP); }
        rowst[NN] = run;
    }
}

// ---- pass B: per coarse bucket: 512-dst LDS hist -> rowst; scatter u16 src
__global__ __launch_bounds__(1024) void k_build2(
    const int* __restrict__ gcnt, const int* __restrict__ gbase,
    const unsigned* __restrict__ cstage,
    int* __restrict__ rowst, unsigned short* __restrict__ csr)
{
    const int b = blockIdx.x;
    const int t = threadIdx.x;
    __shared__ int hist[512], sc[512], curs[512];
    const int cnt = min(gcnt[b], GCAP);
    const int base = gbase[b];
    const int d0 = b << CBSH;
    const int nd = min(512, NN - d0);
    if (t < 512) hist[t] = 0;
    __syncthreads();
    const unsigned* __restrict__ src = cstage + (size_t)b * GCAP;
    for (int i = t; i < cnt; i += 1024)
        atomicAdd(&hist[(src[i] >> 16) & 511], 1);
    __syncthreads();
    if (t < 512) sc[t] = hist[t];
    __syncthreads();
    for (int off = 1; off < 512; off <<= 1) {
        int v = 0;
        if (t < 512 && t >= off) v = sc[t - off];
        __syncthreads();
        if (t < 512) sc[t] += v;
        __syncthreads();
    }
    if (t < 512) {
        int excl = sc[t] - hist[t];
        curs[t] = excl;
        if (t < nd) rowst[d0 + t] = base + excl;
    }
    __syncthreads();
    for (int i = t; i < cnt; i += 1024) {
        unsigned v = src[i];
        int p = atomicAdd(&curs[(v >> 16) & 511], 1);
        csr[base + p] = (unsigned short)(v & 0xFFFFu);
    }
}

// ---- layer-0 fused: 4 edges/wave (slot = lane>>4), 8 fp16 channels/lane (uint4 gather)
__global__ __launch_bounds__(256) void k_agg0(
    const int* __restrict__ rowst, const unsigned short* __restrict__ csr,
    const __half* __restrict__ xl0, const __half* __restrict__ xr0,
    const float* __restrict__ att0, const float* __restrict__ bias0,
    float* __restrict__ h1)
{
    const int d = (blockIdx.x * 256 + threadIdx.x) >> 6;
    const int lane = threadIdx.x & 63;
    if (d >= NN) return;
    const int slot  = lane >> 4;
    const int lane4 = lane & 15;
    const int c0 = lane4 * 8;

    uint4 xrw = *reinterpret_cast<const uint4*>(xr0 + (size_t)d * D1 + c0);
    H2U xr01, xr23, xr45, xr67;
    xr01.u = xrw.x; xr23.u = xrw.y; xr45.u = xrw.z; xr67.u = xrw.w;
    float4 atf0 = *reinterpret_cast<const float4*>(att0 + c0);
    float4 atf1 = *reinterpret_cast<const float4*>(att0 + c0 + 4);
    H2U at01, at23, at45, at67;
    at01.h = __floats2half2_rn(atf0.x, atf0.y);
    at23.h = __floats2half2_rn(atf0.z, atf0.w);
    at45.h = __floats2half2_rn(atf1.x, atf1.y);
    at67.h = __floats2half2_rn(atf1.z, atf1.w);
    const _Float16 kneg = (_Float16)NEG;
    const h2v k2 = { kneg, kneg };

    const int rs = rowst[d];
    const int cnt = rowst[d + 1] - rs;
    float acc0=0.f, acc1=0.f, acc2=0.f, acc3=0.f;
    float acc4=0.f, acc5=0.f, acc6=0.f, acc7=0.f, wsum=0.f;

#define EDGE(W, VALID)                                                      \
    {   H2U x01, x23, x45, x67;                                             \
        x01.u = (W).x; x23.u = (W).y; x45.u = (W).z; x67.u = (W).w;         \
        h2v s01 = x01.v + xr01.v, s23 = x23.v + xr23.v;                     \
        h2v s45 = x45.v + xr45.v, s67 = x67.v + xr67.v;                     \
        h2v l01 = __builtin_elementwise_max(s01, s01 * k2);                 \
        h2v l23 = __builtin_elementwise_max(s23, s23 * k2);                 \
        h2v l45 = __builtin_elementwise_max(s45, s45 * k2);                 \
        h2v l67 = __builtin_elementwise_max(s67, s67 * k2);                 \
        float p = __builtin_amdgcn_fdot2(l01, at01.v,                       \
                  __builtin_amdgcn_fdot2(l23, at23.v,                       \
                  __builtin_amdgcn_fdot2(l45, at45.v,                       \
                  __builtin_amdgcn_fdot2(l67, at67.v, 0.f, false),          \
                  false), false), false);                                   \
        p += __shfl_xor(p, 1);                                              \
        p += __shfl_xor(p, 2);                                              \
        float wgt = (VALID) ? __expf(p) : 0.f;                              \
        float2 f01 = __half22float2(x01.h), f23 = __half22float2(x23.h);    \
        float2 f45 = __half22float2(x45.h), f67 = __half22float2(x67.h);    \
        wsum += wgt;                                                        \
        acc0 += wgt * f01.x; acc1 += wgt * f01.y;                           \
        acc2 += wgt * f23.x; acc3 += wgt * f23.y;                           \
        acc4 += wgt * f45.x; acc5 += wgt * f45.y;                           \
        acc6 += wgt * f67.x; acc7 += wgt * f67.y;                           \
    }

    int i = 0;
    for (; i + 8 <= cnt; i += 8) {
        int s0 = csr[rs + i + slot];
        int s1 = csr[rs + i + 4 + slot];
        uint4 w0 = *reinterpret_cast<const uint4*>(xl0 + (size_t)s0 * D1 + c0);
        uint4 w1 = *reinterpret_cast<const uint4*>(xl0 + (size_t)s1 * D1 + c0);
        EDGE(w0, true);
        EDGE(w1, true);
    }
    for (; i < cnt; i += 4) {
        int e = i + slot;
        bool valid = (e < cnt);
        int s = csr[rs + (valid ? e : 0)];
        uint4 w = *reinterpret_cast<const uint4*>(xl0 + (size_t)s * D1 + c0);
        EDGE(w, valid);
    }
#undef EDGE

#define COMB(V) V += __shfl_xor(V, 16); V += __shfl_xor(V, 32);
    COMB(acc0) COMB(acc1) COMB(acc2) COMB(acc3)
    COMB(acc4) COMB(acc5) COMB(acc6) COMB(acc7)
    COMB(wsum)
#undef COMB

    if (slot == 0) {
        float r = 1.f / (wsum + 1e-16f);
        float4 b0 = *reinterpret_cast<const float4*>(bias0 + c0);
        float4 b1 = *reinterpret_cast<const float4*>(bias0 + c0 + 4);
        float4 o0, o1;
        o0.x = fmaxf(acc0 * r + b0.x, 0.f);
        o0.y = fmaxf(acc1 * r + b0.y, 0.f);
        o0.z = fmaxf(acc2 * r + b0.z, 0.f);
        o0.w = fmaxf(acc3 * r + b0.w, 0.f);
        o1.x = fmaxf(acc4 * r + b1.x, 0.f);
        o1.y = fmaxf(acc5 * r + b1.y, 0.f);
        o1.z = fmaxf(acc6 * r + b1.z, 0.f);
        o1.w = fmaxf(acc7 * r + b1.w, 0.f);
        *reinterpret_cast<float4*>(h1 + (size_t)d * D1 + c0)     = o0;
        *reinterpret_cast<float4*>(h1 + (size_t)d * D1 + c0 + 4) = o1;
    }
}

// ---- GEMM1: xl1 = h1@Wl1+bl1 ; xr1 = h1@Wr1+br1   (thread per node)
__global__ __launch_bounds__(256) void k_gemm1(
    const float* __restrict__ h1,
    const float* __restrict__ Wl, const float* __restrict__ bl,
    const float* __restrict__ Wr, const float* __restrict__ br,
    float* __restrict__ xl1, float* __restrict__ xr1)
{
    __shared__ float wls[D1 * 2], wrs[D1 * 2];
    const int t = threadIdx.x;
    wls[t] = Wl[t]; wrs[t] = Wr[t];
    __syncthreads();
    int n = blockIdx.x * 256 + t;
    if (n >= NN) return;
    float al0 = bl[0], al1 = bl[1], ar0 = br[0], ar1 = br[1];
    const float4* hp = reinterpret_cast<const float4*>(h1 + (size_t)n * D1);
    const float2* wl2 = reinterpret_cast<const float2*>(wls);
    const float2* wr2 = reinterpret_cast<const float2*>(wrs);
#pragma unroll
    for (int k4 = 0; k4 < D1 / 4; ++k4) {
        float4 hv = hp[k4];
        int k = k4 * 4;
        float2 a, b;
        a = wl2[k+0]; b = wr2[k+0]; al0 += hv.x*a.x; al1 += hv.x*a.y; ar0 += hv.x*b.x; ar1 += hv.x*b.y;
        a = wl2[k+1]; b = wr2[k+1]; al0 += hv.y*a.x; al1 += hv.y*a.y; ar0 += hv.y*b.x; ar1 += hv.y*b.y;
        a = wl2[k+2]; b = wr2[k+2]; al0 += hv.z*a.x; al1 += hv.z*a.y; ar0 += hv.z*b.x; ar1 += hv.z*b.y;
        a = wl2[k+3]; b = wr2[k+3]; al0 += hv.w*a.x; al1 += hv.w*a.y; ar0 += hv.w*b.x; ar1 += hv.w*b.y;
    }
    *reinterpret_cast<float2*>(xl1 + (size_t)n * 2) = make_float2(al0, al1);
    *reinterpret_cast<float2*>(xr1 + (size_t)n * 2) = make_float2(ar0, ar1);
}

// ---- layer-1 fused: thread per dst; 4-deep pipelined gather, normalize at end
__global__ __launch_bounds__(256) void k_layer1(
    const int* __restrict__ rowst, const unsigned short* __restrict__ csr,
    const float* __restrict__ xl1, const float* __restrict__ xr1,
    const float* __restrict__ att1, const float* __restrict__ bias1,
    float* __restrict__ out)
{
    int d = blockIdx.x * 256 + threadIdx.x;
    if (d >= NN) return;
    float2 xr = *reinterpret_cast<const float2*>(xr1 + (size_t)d * 2);
    float A0 = att1[0], A1 = att1[1];
    int rs = rowst[d], re = rowst[d + 1];
    float sum = 0.f, a0 = 0.f, a1 = 0.f;
    int i = rs;
    for (; i + 4 <= re; i += 4) {
        int s0 = csr[i], s1 = csr[i+1], s2 = csr[i+2], s3 = csr[i+3];
        float2 x0 = *reinterpret_cast<const float2*>(xl1 + (size_t)s0 * 2);
        float2 x1 = *reinterpret_cast<const float2*>(xl1 + (size_t)s1 * 2);
        float2 x2 = *reinterpret_cast<const float2*>(xl1 + (size_t)s2 * 2);
        float2 x3 = *reinterpret_cast<const float2*>(xl1 + (size_t)s3 * 2);
        float w0 = __expf(lrelu(x0.x + xr.x) * A0 + lrelu(x0.y + xr.y) * A1);
        float w1 = __expf(lrelu(x1.x + xr.x) * A0 + lrelu(x1.y + xr.y) * A1);
        float w2 = __expf(lrelu(x2.x + xr.x) * A0 + lrelu(x2.y + xr.y) * A1);
        float w3 = __expf(lrelu(x3.x + xr.x) * A0 + lrelu(x3.y + xr.y) * A1);
        sum += w0 + w1 + w2 + w3;
        a0 += w0 * x0.x + w1 * x1.x + w2 * x2.x + w3 * x3.x;
        a1 += w0 * x0.y + w1 * x1.y + w2 * x2.y + w3 * x3.y;
    }
    for (; i < re; ++i) {
        int s = csr[i];
        float2 xs = *reinterpret_cast<const float2*>(xl1 + (size_t)s * 2);
        float wgt = __expf(lrelu(xs.x + xr.x) * A0 + lrelu(xs.y + xr.y) * A1);
        sum += wgt;
        a0 += wgt * xs.x;
        a1 += wgt * xs.y;
    }
    float r = 1.f / (sum + 1e-16f);
    out[(size_t)d * 2]     = a0 * r + bias1[0];
    out[(size_t)d * 2 + 1] = a1 * r + bias1[1];
}

extern "C" void kernel_launch(void* const* d_in, const int* in_sizes, int n_in,
                              void* d_out, int out_size, void* d_ws, size_t ws_size,
                              hipStream_t stream)
{
    const float* x     = (const float*)d_in[0];
    const int*   ei    = (const int*)d_in[1];
    const int*   ts    = (const int*)d_in[2];
    const float* Wt    = (const float*)d_in[3];
    const float* Wl0   = (const float*)d_in[4];
    const float* bl0   = (const float*)d_in[5];
    const float* Wr0   = (const float*)d_in[6];
    const float* br0   = (const float*)d_in[7];
    const float* att0  = (const float*)d_in[8];
    const float* bias0 = (const float*)d_in[9];
    const float* Wl1   = (const float*)d_in[10];
    const float* bl1   = (const float*)d_in[11];
    const float* Wr1   = (const float*)d_in[12];
    const float* br1   = (const float*)d_in[13];
    const float* att1  = (const float*)d_in[14];
    const float* bias1 = (const float*)d_in[15];
    float* out = (float*)d_out;

    char* wsp = (char*)d_ws;
    size_t off = 0;
    auto alloc = [&](size_t bytes) -> void* {
        void* p = wsp + off;
        off += (bytes + 255) & ~(size_t)255;
        return p;
    };
    __half* xl0  = (__half*)alloc((size_t)NN * D1 * 2);
    __half* xr0  = (__half*)alloc((size_t)NN * D1 * 2);
    float* h1    = (float*)alloc((size_t)NN * D1 * 4);
    float* xl1   = (float*)alloc((size_t)NN * 2 * 4);
    float* xr1   = (float*)alloc((size_t)NN * 2 * 4);
    int* rowst   = (int*)alloc((size_t)(NN + 1) * 4);
    unsigned short* csr = (unsigned short*)alloc((size_t)EP * 2);
    int* gcnt        = (int*)alloc((size_t)NCB * 4);
    int* gbase       = (int*)alloc((size_t)NCB * 4);
    unsigned* cstage = (unsigned*)alloc((size_t)NCB * GCAP * 4);
    __half* Btg      = (__half*)alloc((size_t)256 * INDIM * 2);
    float* bcat      = (float*)alloc((size_t)256 * 4);

    k_wcast<<<(256 * INDIM + 255) / 256, 256, 0, stream>>>(Wl0, Wr0, bl0, br0, Btg, bcat);
    k_gemm0m<<<(NN + MT - 1) / MT, 256, 0, stream>>>(x, ts, Wt, Btg, bcat, xl0, xr0);

    (void)hipMemsetAsync(gcnt, 0, (size_t)NCB * 4, stream);
    const int ntiles = (EP + TILE - 1) / TILE;
    k_part<<<ntiles, 1024, 0, stream>>>(ei, gcnt, cstage);
    k_cscan<<<1, 64, 0, stream>>>(gcnt, gbase, rowst);
    k_build2<<<NCB, 1024, 0, stream>>>(gcnt, gbase, cstage, rowst, csr);

    k_agg0<<<(NN + 3) / 4, 256, 0, stream>>>(rowst, csr, xl0, xr0, att0, bias0, h1);
    k_gemm1<<<(NN + 255) / 256, 256, 0, stream>>>(h1, Wl1, bl1, Wr1, br1, xl1, xr1);
    k_layer1<<<(NN + 255) / 256, 256, 0, stream>>>(rowst, csr, xl1, xr1, att1, bias1, out);
}